// Round 21
// baseline (170.941 us; speedup 1.0000x reference)
//
#include <hip/hip_runtime.h>

// RES=[64,128,256,512,1024], NF=8, NC=2, P=1e6. out[p*40 + lvl*8 + c], fp32.
//
// Primary pipeline (bf16, scale-free — memset + 4 kernels):
//  memset(cursor+ovf_cnt)
//  K1a scatter_bins (64 x 512, 32KB LDS): LDS histogram -> ONE global
//      atomicAdd per (block,bin) -> placement writes 12B slots {xn,yn,perm}.
//  K1b transform (10912 x 256, no LDS): fp32 -> bf16 channel-last uint4/px.
//  K4  tile sample (1024 blocks = 2x2-bin groups, plain launch_bounds(256)):
//      block stages its 1/32-tile L0-L3 window into LDS and serves ~976
//      points (4 iters/thread, pipelined). Round-20 lesson: worst-case
//      fractional offsets give 1480 uint4 (NOT 1288 — f->1 makes L3 21x21),
//      which overflowed the 1408 cap silently -> LDS corruption. Cap is now
//      1536 (24.5KB) AND the use_lds runtime guard is back (global fallback,
//      block-uniform, never taken).
//      L4 direct from bf16 global (L2/L3-resident).
//  K5  overflow kernel (32 blocks): identical-arithmetic global path.
// Fallbacks: int8 pipeline (ws>=37.9MB), else direct fp32.
//
// ws layout (bytes):
//   cursor[4096]@0  ovf_cnt@16384  deq[8]@16448  inv[8]@16480
//   partials[5456]@20480  ovf[131072]@65536
//   slots[4096*304]x12B@589824  tables@15532032
//   (bf16 tables end @60227584; int8 end @37879808)

#define WS_CURS 0
#define WS_OVFC 16384
#define WS_DEQ 16448
#define WS_INV 16480
#define WS_PART 20480
#define WS_OVF 65536
#define WS_SLOT 589824
#define WS_TAB 15532032
#define WS_END_BF16 60227584ull
#define WS_END_I8 37879808ull
#define NGRP 4096
#define CAP 304
#define OVF_CAP 131072
#define LDS_CAP 1600    // uint2 slots for i8 fallback (12.8KB)
#define LDS_CAP4 1536   // uint4 slots (24.5KB) >= true worst case 1480
#define NSCAT 64
#define NSCAT_I8 2048

typedef __attribute__((ext_vector_type(8))) unsigned short ushort8v;

__device__ __forceinline__ unsigned short f2bf(float f) {
  union { float f; unsigned u; } c; c.f = f;
  unsigned u = c.u;
  u += 0x7FFFu + ((u >> 16) & 1u);   // RNE
  return (unsigned short)(u >> 16);
}

__device__ __forceinline__ int bin_of(float xv, float yv) {
  int bx = min(max((int)(xv * 128.0f), 0), 127);
  int by = min(max((int)(yv * 128.0f), 0), 127);
  return (by >> 1) * 64 + (bx >> 1);
}

// legacy per-point scatter (int8 fallback path only)
__device__ __forceinline__ void scatter_one(
    const float* __restrict__ x, const float* __restrict__ y, int p,
    unsigned* __restrict__ cursor, unsigned* __restrict__ ovf_cnt,
    int* __restrict__ ovf, float* __restrict__ slots) {
  float xv = x[p], yv = y[p];
  int g = bin_of(xv, yv);
  unsigned s = atomicAdd(&cursor[g], 1u);
  if (s < CAP) {
    float* sp = slots + ((size_t)g * CAP + s) * 3u;
    sp[0] = xv * 2.0f - 1.0f;
    sp[1] = yv * 2.0f - 1.0f;
    sp[2] = __int_as_float(p);
  } else {
    unsigned o = atomicAdd(ovf_cnt, 1u);
    if (o < OVF_CAP) ovf[o] = p;
  }
}

// ==== K1a: LDS-aggregated counting scatter ====
__global__ __launch_bounds__(512) void scatter_bins_kernel(
    const float* __restrict__ x, const float* __restrict__ y, int P,
    unsigned* __restrict__ cursor, unsigned* __restrict__ ovf_cnt,
    int* __restrict__ ovf, float* __restrict__ slots) {
  __shared__ unsigned cnt[NGRP];    // 16 KB
  __shared__ unsigned base[NGRP];   // 16 KB
  int b = blockIdx.x;
  int tid = (int)threadIdx.x;
  int chunk = (P + NSCAT - 1) / NSCAT;
  int lo = b * chunk;
  int hi = min(lo + chunk, P);
  for (int i = tid; i < NGRP; i += 512) cnt[i] = 0u;
  __syncthreads();
  for (int p = lo + tid; p < hi; p += 512)
    atomicAdd(&cnt[bin_of(x[p], y[p])], 1u);
  __syncthreads();
  for (int g = tid; g < NGRP; g += 512) {
    unsigned c = cnt[g];
    base[g] = c ? atomicAdd(&cursor[g], c) : 0u;
  }
  __syncthreads();
  for (int i = tid; i < NGRP; i += 512) cnt[i] = 0u;
  __syncthreads();
  for (int p = lo + tid; p < hi; p += 512) {
    float xv = x[p], yv = y[p];
    int g = bin_of(xv, yv);
    unsigned r = atomicAdd(&cnt[g], 1u);
    unsigned idx = base[g] + r;
    if (idx < CAP) {
      float* sp = slots + ((size_t)g * CAP + idx) * 3u;
      sp[0] = xv * 2.0f - 1.0f;
      sp[1] = yv * 2.0f - 1.0f;
      sp[2] = __int_as_float(p);
    } else {
      unsigned o = atomicAdd(ovf_cnt, 1u);
      if (o < OVF_CAP) ovf[o] = p;
    }
  }
}

// ==== K1b: transform (no LDS -> full streaming occupancy) ====
__global__ __launch_bounds__(256) void transform_kernel(
    const float* __restrict__ s0, const float* __restrict__ s1,
    const float* __restrict__ s2, const float* __restrict__ s3,
    const float* __restrict__ s4, uint4* __restrict__ tb) {
  int b = blockIdx.x;
  const float* src; int HW; int lb; size_t toff;
  if (b < 32)        { src = s0; HW = 4096;    lb = 0;    toff = 0; }
  else if (b < 160)  { src = s1; HW = 16384;   lb = 32;   toff = 8192; }
  else if (b < 672)  { src = s2; HW = 65536;   lb = 160;  toff = 40960; }
  else if (b < 2720) { src = s3; HW = 262144;  lb = 672;  toff = 172032; }
  else               { src = s4; HW = 1048576; lb = 2720; toff = 696320; }
  int i = (b - lb) * 256 + (int)threadIdx.x;
  int cell = i / HW;
  int pix = i - cell * HW;
  const float* s = src + (size_t)cell * 8u * (size_t)HW + (size_t)pix;
  ushort8v v;
#pragma unroll
  for (int ch = 0; ch < 8; ++ch) v[ch] = f2bf(s[(size_t)ch * HW]);
  ((ushort8v*)tb)[toff + (size_t)i] = v;
}

// ==== shared window machinery ====
struct Win { int ixmin, iymin, ww, wh, base; };

template <int W>
__device__ __forceinline__ Win mkwin(float xlo, float xhi, float ylo, float yhi,
                                     int base) {
  const float s = (float)(W - 1);
  Win w;
  w.ixmin = max(0, (int)floorf(xlo * s) - 1);
  int ixmax = min(W - 1, (int)floorf(xhi * s + 0.5f) + 2);
  w.iymin = max(0, (int)floorf(ylo * s) - 1);
  int iymax = min(W - 1, (int)floorf(yhi * s + 0.5f) + 2);
  w.ww = ixmax - w.ixmin + 1;
  w.wh = iymax - w.iymin + 1;
  w.base = base;
  return w;
}

__device__ __forceinline__ void store8(float* __restrict__ o,
                                       const float* __restrict__ r) {
  ((float4*)o)[0] = make_float4(r[0], r[1], r[2], r[3]);
  ((float4*)o)[1] = make_float4(r[4], r[5], r[6], r[7]);
}

// ==== bf16 path ====
template <int W>
__device__ __forceinline__ void stage_bf16(uint4* __restrict__ lds, const Win& w,
                                           const uint4* __restrict__ t) {
  int n = w.ww * w.wh;
  for (int j = (int)threadIdx.x; j < 2 * n; j += 256) {
    int cell = j >= n;
    int jj = cell ? j - n : j;
    int r = jj / w.ww;
    int c = jj - r * w.ww;
    lds[w.base + j] = t[cell * W * W + (w.iymin + r) * W + (w.ixmin + c)];
  }
}

__device__ __forceinline__ void fma_bf(uint4 v, float w, float* __restrict__ acc) {
  acc[0] = fmaf(__uint_as_float(v.x << 16), w, acc[0]);
  acc[1] = fmaf(__uint_as_float(v.x & 0xFFFF0000u), w, acc[1]);
  acc[2] = fmaf(__uint_as_float(v.y << 16), w, acc[2]);
  acc[3] = fmaf(__uint_as_float(v.y & 0xFFFF0000u), w, acc[3]);
  acc[4] = fmaf(__uint_as_float(v.z << 16), w, acc[4]);
  acc[5] = fmaf(__uint_as_float(v.z & 0xFFFF0000u), w, acc[5]);
  acc[6] = fmaf(__uint_as_float(v.w << 16), w, acc[6]);
  acc[7] = fmaf(__uint_as_float(v.w & 0xFFFF0000u), w, acc[7]);
}

template <int W>
__device__ __forceinline__ void sample_bf_lds(const uint4* __restrict__ lds,
                                              const Win& w, float xn, float yn,
                                              float* __restrict__ res) {
  const float s = (float)(W - 1);
  float acc[8];
#pragma unroll
  for (int i = 0; i < 8; ++i) acc[i] = 0.0f;
#pragma unroll
  for (int cell = 0; cell < 2; ++cell) {
    const float off = 0.5f * (float)cell;
    float ix = (xn + 1.0f) * 0.5f * s + off;
    float iy = (yn + 1.0f) * 0.5f * s + off;
    float xf = floorf(ix), yf = floorf(iy);
    float wx = ix - xf, wy = iy - yf;
    int x0 = min(max((int)xf, 0), W - 1);
    int y0 = min(max((int)yf, 0), W - 1);
    int x1 = min(x0 + 1, W - 1);
    int y1 = min(y0 + 1, W - 1);
    int cb = w.base + cell * (w.ww * w.wh) - w.ixmin;
    int r0 = cb + (y0 - w.iymin) * w.ww;
    int r1 = cb + (y1 - w.iymin) * w.ww;
    uint4 c00 = lds[r0 + x0], c01 = lds[r0 + x1];
    uint4 c10 = lds[r1 + x0], c11 = lds[r1 + x1];
    float w00 = (1.0f - wx) * (1.0f - wy);
    float w01 = wx * (1.0f - wy);
    float w10 = (1.0f - wx) * wy;
    float w11 = wx * wy;
    fma_bf(c00, w00, acc);
    fma_bf(c01, w01, acc);
    fma_bf(c10, w10, acc);
    fma_bf(c11, w11, acc);
  }
#pragma unroll
  for (int i = 0; i < 8; ++i) res[i] = acc[i];
}

template <int W>
__device__ __forceinline__ void sample_bf_glob(const uint4* __restrict__ t,
                                               float xn, float yn,
                                               float* __restrict__ res) {
  const float s = (float)(W - 1);
  float acc[8];
#pragma unroll
  for (int i = 0; i < 8; ++i) acc[i] = 0.0f;
#pragma unroll
  for (int cell = 0; cell < 2; ++cell) {
    const float off = 0.5f * (float)cell;
    float ix = (xn + 1.0f) * 0.5f * s + off;
    float iy = (yn + 1.0f) * 0.5f * s + off;
    float xf = floorf(ix), yf = floorf(iy);
    float wx = ix - xf, wy = iy - yf;
    int x0 = min(max((int)xf, 0), W - 1);
    int y0 = min(max((int)yf, 0), W - 1);
    int x1 = min(x0 + 1, W - 1);
    int y1 = min(y0 + 1, W - 1);
    const uint4* b = t + cell * W * W;
    uint4 c00 = b[y0 * W + x0], c01 = b[y0 * W + x1];
    uint4 c10 = b[y1 * W + x0], c11 = b[y1 * W + x1];
    float w00 = (1.0f - wx) * (1.0f - wy);
    float w01 = wx * (1.0f - wy);
    float w10 = (1.0f - wx) * wy;
    float w11 = wx * wy;
    fma_bf(c00, w00, acc);
    fma_bf(c01, w01, acc);
    fma_bf(c10, w10, acc);
    fma_bf(c11, w11, acc);
  }
#pragma unroll
  for (int i = 0; i < 8; ++i) res[i] = acc[i];
}

// K4: tile sample — one block per 2x2-bin group (1/32 tile), 4 bins' points.
__global__ __launch_bounds__(256) void sample_tile_bf16(
    const float* __restrict__ slots, const unsigned* __restrict__ cursor,
    const uint4* __restrict__ t0, const uint4* __restrict__ t1,
    const uint4* __restrict__ t2, const uint4* __restrict__ t3,
    const uint4* __restrict__ t4, float* __restrict__ out) {
  __shared__ uint4 lds[LDS_CAP4];
  int g2 = blockIdx.x;          // 0..1023
  int gx2 = g2 & 31, gy2 = g2 >> 5;
  int b00 = (2 * gy2) * 64 + 2 * gx2;
  int bins[4] = {b00, b00 + 1, b00 + 64, b00 + 65};
  int cnts[4];
  int total_pts = 0;
#pragma unroll
  for (int k = 0; k < 4; ++k) {
    cnts[k] = min((int)cursor[bins[k]], CAP);
    total_pts += cnts[k];
  }
  if (total_pts == 0) return;

  float xlo = (float)gx2 * (1.0f / 32.0f);
  float xhi = (float)(gx2 + 1) * (1.0f / 32.0f);
  float ylo = (float)gy2 * (1.0f / 32.0f);
  float yhi = (float)(gy2 + 1) * (1.0f / 32.0f);

  // L0-L3 windows; worst case 1480 uint4 <= 1536 (adversarial fractional
  // offsets included — round-20 lesson). Guard kept for safety.
  Win w0 = mkwin<64>(xlo, xhi, ylo, yhi, 0);
  Win w1 = mkwin<128>(xlo, xhi, ylo, yhi, w0.base + 2 * w0.ww * w0.wh);
  Win w2 = mkwin<256>(xlo, xhi, ylo, yhi, w1.base + 2 * w1.ww * w1.wh);
  Win w3 = mkwin<512>(xlo, xhi, ylo, yhi, w2.base + 2 * w2.ww * w2.wh);
  int total = w3.base + 2 * w3.ww * w3.wh;
  bool use_lds = (total <= LDS_CAP4);

  if (use_lds) {
    stage_bf16<64>(lds, w0, t0);
    stage_bf16<128>(lds, w1, t1);
    stage_bf16<256>(lds, w2, t2);
    stage_bf16<512>(lds, w3, t3);
    __syncthreads();
  }

#pragma unroll
  for (int k = 0; k < 4; ++k) {
    int cnt = cnts[k];
    const float* gs = slots + (size_t)bins[k] * CAP * 3u;
    for (int i = (int)threadIdx.x; i < cnt; i += 256) {
      const float* sp = gs + (size_t)i * 3u;
      float xn = sp[0], yn = sp[1];
      float* orow = out + (size_t)__float_as_int(sp[2]) * 40u;
      float res[8];
      if (use_lds) {
        sample_bf_lds<64>(lds, w0, xn, yn, res);   store8(orow + 0, res);
        sample_bf_lds<128>(lds, w1, xn, yn, res);  store8(orow + 8, res);
        sample_bf_lds<256>(lds, w2, xn, yn, res);  store8(orow + 16, res);
        sample_bf_lds<512>(lds, w3, xn, yn, res);  store8(orow + 24, res);
      } else {
        sample_bf_glob<64>(t0, xn, yn, res);   store8(orow + 0, res);
        sample_bf_glob<128>(t1, xn, yn, res);  store8(orow + 8, res);
        sample_bf_glob<256>(t2, xn, yn, res);  store8(orow + 16, res);
        sample_bf_glob<512>(t3, xn, yn, res);  store8(orow + 24, res);
      }
      sample_bf_glob<1024>(t4, xn, yn, res);   store8(orow + 32, res);
    }
  }
}

// K5: overflow stragglers (expected 0) — identical arithmetic.
__global__ __launch_bounds__(256) void sample_ovf_bf16(
    const unsigned* __restrict__ ovf_cnt, const int* __restrict__ ovf,
    const float* __restrict__ x, const float* __restrict__ y,
    const uint4* __restrict__ t0, const uint4* __restrict__ t1,
    const uint4* __restrict__ t2, const uint4* __restrict__ t3,
    const uint4* __restrict__ t4, float* __restrict__ out) {
  int n = min((int)*ovf_cnt, OVF_CAP);
  int stride = gridDim.x * 256;
  for (int i = blockIdx.x * 256 + (int)threadIdx.x; i < n; i += stride) {
    int p = ovf[i];
    float xn = x[p] * 2.0f - 1.0f;
    float yn = y[p] * 2.0f - 1.0f;
    float* orow = out + (size_t)p * 40u;
    float res[8];
    sample_bf_glob<64>(t0, xn, yn, res);   store8(orow + 0, res);
    sample_bf_glob<128>(t1, xn, yn, res);  store8(orow + 8, res);
    sample_bf_glob<256>(t2, xn, yn, res);  store8(orow + 16, res);
    sample_bf_glob<512>(t3, xn, yn, res);  store8(orow + 24, res);
    sample_bf_glob<1024>(t4, xn, yn, res); store8(orow + 32, res);
  }
}

// ==== int8 fallback path ====
__global__ __launch_bounds__(256) void absmax_scatter_kernel(
    const float* __restrict__ s0, const float* __restrict__ s1,
    const float* __restrict__ s2, const float* __restrict__ s3,
    const float* __restrict__ s4, unsigned* __restrict__ partials,
    const float* __restrict__ x, const float* __restrict__ y, int P,
    unsigned* __restrict__ cursor, unsigned* __restrict__ ovf_cnt,
    int* __restrict__ ovf, float* __restrict__ slots) {
  int b = blockIdx.x;
  if (b < NSCAT_I8) {
    int stride = NSCAT_I8 * 256;
    for (int p = b * 256 + (int)threadIdx.x; p < P; p += stride)
      scatter_one(x, y, p, cursor, ovf_cnt, ovf, slots);
    return;
  }
  int bb = b - NSCAT_I8;
  __shared__ unsigned red[4];
  const float* src; int n4; int lb; int nb;
  if (bb < 16)        { src = s0; n4 = 16384;   lb = 0;    nb = 16; }
  else if (bb < 80)   { src = s1; n4 = 65536;   lb = 16;   nb = 64; }
  else if (bb < 336)  { src = s2; n4 = 262144;  lb = 80;   nb = 256; }
  else if (bb < 1360) { src = s3; n4 = 1048576; lb = 336;  nb = 1024; }
  else                { src = s4; n4 = 4194304; lb = 1360; nb = 4096; }
  int local = bb - lb;
  unsigned m = 0;
  for (int k = local * 256 + threadIdx.x; k < n4; k += nb * 256) {
    float4 v = ((const float4*)src)[k];
    unsigned a = __float_as_uint(v.x) & 0x7FFFFFFFu;
    unsigned c = __float_as_uint(v.y) & 0x7FFFFFFFu;
    unsigned d = __float_as_uint(v.z) & 0x7FFFFFFFu;
    unsigned e = __float_as_uint(v.w) & 0x7FFFFFFFu;
    m = max(m, max(max(a, c), max(d, e)));
  }
#pragma unroll
  for (int off = 32; off; off >>= 1)
    m = max(m, (unsigned)__shfl_xor((int)m, off));
  if ((threadIdx.x & 63) == 0) red[threadIdx.x >> 6] = m;
  __syncthreads();
  if (threadIdx.x == 0)
    partials[bb] = max(max(red[0], red[1]), max(red[2], red[3]));
}

__global__ __launch_bounds__(256) void finalize_scales_kernel(
    const unsigned* __restrict__ partials, float* __restrict__ deq,
    float* __restrict__ inv) {
  __shared__ unsigned red[4];
  int t = (int)threadIdx.x;
  const int lo[5] = {0, 16, 80, 336, 1360};
  const int hi[5] = {16, 80, 336, 1360, 5456};
  for (int l = 0; l < 5; ++l) {
    unsigned m = 0;
    for (int i = lo[l] + t; i < hi[l]; i += 256) m = max(m, partials[i]);
#pragma unroll
    for (int off = 32; off; off >>= 1)
      m = max(m, (unsigned)__shfl_xor((int)m, off));
    if ((t & 63) == 0) red[t >> 6] = m;
    __syncthreads();
    if (t == 0) {
      unsigned r = max(max(red[0], red[1]), max(red[2], red[3]));
      float s = __uint_as_float(r);
      if (!(s > 0.0f)) s = 1e-20f;
      deq[l] = s / 127.0f;
      inv[l] = 127.0f / s;
    }
    __syncthreads();
  }
}

__global__ __launch_bounds__(256) void quant_kernel(
    const float* __restrict__ s0, const float* __restrict__ s1,
    const float* __restrict__ s2, const float* __restrict__ s3,
    const float* __restrict__ s4, uint2* __restrict__ tb,
    const float* __restrict__ invp) {
  int b = blockIdx.x;
  const float* src; int HW; int lb; int l; size_t toff;
  if (b < 32)        { src = s0; HW = 4096;    lb = 0;    l = 0; toff = 0; }
  else if (b < 160)  { src = s1; HW = 16384;   lb = 32;   l = 1; toff = 8192; }
  else if (b < 672)  { src = s2; HW = 65536;   lb = 160;  l = 2; toff = 40960; }
  else if (b < 2720) { src = s3; HW = 262144;  lb = 672;  l = 3; toff = 172032; }
  else               { src = s4; HW = 1048576; lb = 2720; l = 4; toff = 696320; }
  int i = (b - lb) * 256 + (int)threadIdx.x;
  float sc = invp[l];
  int cell = i / HW;
  int pix = i - cell * HW;
  const float* s = src + (size_t)cell * 8u * (size_t)HW + (size_t)pix;
  unsigned lov = 0, hiv = 0;
#pragma unroll
  for (int c = 0; c < 4; ++c) {
    int q = (int)rintf(s[(size_t)c * HW] * sc);
    q = min(max(q, -127), 127);
    lov |= ((unsigned)(q & 0xFF)) << (8 * c);
  }
#pragma unroll
  for (int c = 0; c < 4; ++c) {
    int q = (int)rintf(s[(size_t)(c + 4) * HW] * sc);
    q = min(max(q, -127), 127);
    hiv |= ((unsigned)(q & 0xFF)) << (8 * c);
  }
  tb[toff + (size_t)i] = make_uint2(lov, hiv);
}

template <int W>
__device__ __forceinline__ void stage_i8(uint2* __restrict__ lds, const Win& w,
                                         const uint2* __restrict__ t) {
  int n = w.ww * w.wh;
  for (int i = (int)threadIdx.x; i < 2 * n; i += 256) {
    int cell = i >= n;
    int j = cell ? i - n : i;
    int r = j / w.ww;
    int c = j - r * w.ww;
    lds[w.base + i] = t[cell * W * W + (w.iymin + r) * W + (w.ixmin + c)];
  }
}

__device__ __forceinline__ void fma_i8(unsigned lo, unsigned hi, float w,
                                       float* __restrict__ acc) {
#pragma unroll
  for (int c = 0; c < 4; ++c)
    acc[c] = fmaf((float)(signed char)(lo >> (8 * c)), w, acc[c]);
#pragma unroll
  for (int c = 0; c < 4; ++c)
    acc[4 + c] = fmaf((float)(signed char)(hi >> (8 * c)), w, acc[4 + c]);
}

template <int W>
__device__ __forceinline__ void sample_i8(const uint2* __restrict__ lds,
                                          const Win& w, bool use_lds,
                                          const uint2* __restrict__ t,
                                          float xn, float yn, float deq,
                                          float* __restrict__ res) {
  const float s = (float)(W - 1);
  float acc[8];
#pragma unroll
  for (int i = 0; i < 8; ++i) acc[i] = 0.0f;
#pragma unroll
  for (int cell = 0; cell < 2; ++cell) {
    const float off = 0.5f * (float)cell;
    float ix = (xn + 1.0f) * 0.5f * s + off;
    float iy = (yn + 1.0f) * 0.5f * s + off;
    float xf = floorf(ix), yf = floorf(iy);
    float wx = ix - xf, wy = iy - yf;
    int x0 = min(max((int)xf, 0), W - 1);
    int y0 = min(max((int)yf, 0), W - 1);
    int x1 = min(x0 + 1, W - 1);
    int y1 = min(y0 + 1, W - 1);
    uint2 c00, c01, c10, c11;
    if (use_lds) {
      int cb = w.base + cell * (w.ww * w.wh) - w.ixmin;
      int r0 = cb + (y0 - w.iymin) * w.ww;
      int r1 = cb + (y1 - w.iymin) * w.ww;
      c00 = lds[r0 + x0]; c01 = lds[r0 + x1];
      c10 = lds[r1 + x0]; c11 = lds[r1 + x1];
    } else {
      const uint2* b = t + cell * W * W;
      c00 = b[y0 * W + x0]; c01 = b[y0 * W + x1];
      c10 = b[y1 * W + x0]; c11 = b[y1 * W + x1];
    }
    float w00 = (1.0f - wx) * (1.0f - wy);
    float w01 = wx * (1.0f - wy);
    float w10 = (1.0f - wx) * wy;
    float w11 = wx * wy;
    fma_i8(c00.x, c00.y, w00, acc);
    fma_i8(c01.x, c01.y, w01, acc);
    fma_i8(c10.x, c10.y, w10, acc);
    fma_i8(c11.x, c11.y, w11, acc);
  }
#pragma unroll
  for (int i = 0; i < 8; ++i) res[i] = acc[i] * deq;
}

__global__ __launch_bounds__(256) void sample_tile_i8(
    const float* __restrict__ slots, const unsigned* __restrict__ cursor,
    const unsigned* __restrict__ ovf_cnt, const int* __restrict__ ovf,
    const float* __restrict__ x, const float* __restrict__ y,
    const uint2* __restrict__ t0, const uint2* __restrict__ t1,
    const uint2* __restrict__ t2, const uint2* __restrict__ t3,
    const uint2* __restrict__ t4, const float* __restrict__ deqs,
    float* __restrict__ out, int P) {
  __shared__ uint2 lds[LDS_CAP];
  int g = blockIdx.x;
  float d0 = deqs[0], d1 = deqs[1], d2 = deqs[2], d3 = deqs[3], d4 = deqs[4];
  Win wdum = {0, 0, 1, 1, 0};

  if (g >= NGRP) {
    int n = min((int)*ovf_cnt, OVF_CAP);
    int stride = (gridDim.x - NGRP) * 256;
    for (int i = (g - NGRP) * 256 + (int)threadIdx.x; i < n; i += stride) {
      int p = ovf[i];
      float xn = x[p] * 2.0f - 1.0f;
      float yn = y[p] * 2.0f - 1.0f;
      float* orow = out + (size_t)p * 40u;
      float res[8];
      sample_i8<64>(lds, wdum, false, t0, xn, yn, d0, res);   store8(orow + 0, res);
      sample_i8<128>(lds, wdum, false, t1, xn, yn, d1, res);  store8(orow + 8, res);
      sample_i8<256>(lds, wdum, false, t2, xn, yn, d2, res);  store8(orow + 16, res);
      sample_i8<512>(lds, wdum, false, t3, xn, yn, d3, res);  store8(orow + 24, res);
      sample_i8<1024>(lds, wdum, false, t4, xn, yn, d4, res); store8(orow + 32, res);
    }
    return;
  }

  int cnt = min((int)cursor[g], CAP);
  if (cnt == 0) return;

  int gx = g & 63, gy = g >> 6;
  float xlo = (float)gx * (1.0f / 64.0f);
  float xhi = (float)(gx + 1) * (1.0f / 64.0f);
  float ylo = (float)gy * (1.0f / 64.0f);
  float yhi = (float)(gy + 1) * (1.0f / 64.0f);

  Win w0 = mkwin<64>(xlo, xhi, ylo, yhi, 0);
  Win w1 = mkwin<128>(xlo, xhi, ylo, yhi, w0.base + 2 * w0.ww * w0.wh);
  Win w2 = mkwin<256>(xlo, xhi, ylo, yhi, w1.base + 2 * w1.ww * w1.wh);
  Win w3 = mkwin<512>(xlo, xhi, ylo, yhi, w2.base + 2 * w2.ww * w2.wh);
  Win w4 = mkwin<1024>(xlo, xhi, ylo, yhi, w3.base + 2 * w3.ww * w3.wh);
  int total = w4.base + 2 * w4.ww * w4.wh;
  bool use_lds = (total <= LDS_CAP);

  if (use_lds) {
    stage_i8<64>(lds, w0, t0);
    stage_i8<128>(lds, w1, t1);
    stage_i8<256>(lds, w2, t2);
    stage_i8<512>(lds, w3, t3);
    stage_i8<1024>(lds, w4, t4);
    __syncthreads();
  }

  const float* gs = slots + (size_t)g * CAP * 3u;
  for (int i = (int)threadIdx.x; i < cnt; i += 256) {
    const float* sp = gs + (size_t)i * 3u;
    float xn = sp[0], yn = sp[1];
    int q = __float_as_int(sp[2]);
    float* orow = out + (size_t)q * 40u;
    float res[8];
    sample_i8<64>(lds, w0, use_lds, t0, xn, yn, d0, res);   store8(orow + 0, res);
    sample_i8<128>(lds, w1, use_lds, t1, xn, yn, d1, res);  store8(orow + 8, res);
    sample_i8<256>(lds, w2, use_lds, t2, xn, yn, d2, res);  store8(orow + 16, res);
    sample_i8<512>(lds, w3, use_lds, t3, xn, yn, d3, res);  store8(orow + 24, res);
    sample_i8<1024>(lds, w4, use_lds, t4, xn, yn, d4, res); store8(orow + 32, res);
  }
}

// ==== tiny-ws fallback: direct fp32 ====
template <int W>
__device__ __forceinline__ void sample_level_direct(
    const float* __restrict__ t, float xv, float yv, float* __restrict__ o) {
  float acc[8];
#pragma unroll
  for (int i = 0; i < 8; ++i) acc[i] = 0.0f;
  float xn = xv * 2.0f - 1.0f;
  float yn = yv * 2.0f - 1.0f;
#pragma unroll
  for (int cell = 0; cell < 2; ++cell) {
    const float off = 0.5f * (float)cell;
    float ix = (xn + 1.0f) * 0.5f * (float)(W - 1) + off;
    float iy = (yn + 1.0f) * 0.5f * (float)(W - 1) + off;
    float x0f = floorf(ix), y0f = floorf(iy);
    float wx = ix - x0f, wy = iy - y0f;
    int x0 = (int)x0f; x0 = min(max(x0, 0), W - 1);
    int y0 = (int)y0f; y0 = min(max(y0, 0), W - 1);
    int x1 = min(x0 + 1, W - 1);
    int y1 = min(y0 + 1, W - 1);
    float w00 = (1.0f - wx) * (1.0f - wy);
    float w01 = wx * (1.0f - wy);
    float w10 = (1.0f - wx) * wy;
    float w11 = wx * wy;
    size_t i00 = (size_t)y0 * W + x0;
    size_t i01 = (size_t)y0 * W + x1;
    size_t i10 = (size_t)y1 * W + x0;
    size_t i11 = (size_t)y1 * W + x1;
#pragma unroll
    for (int c = 0; c < 8; ++c) {
      const float* pc = t + (size_t)cell * 8u * (size_t)W * (size_t)W +
                        (size_t)c * (size_t)W * (size_t)W;
      acc[c] += pc[i00] * w00 + pc[i01] * w01 + pc[i10] * w10 + pc[i11] * w11;
    }
  }
#pragma unroll
  for (int i = 0; i < 8; ++i) o[i] = acc[i];
}

__global__ __launch_bounds__(256) void sample_kernel_direct(
    const float* __restrict__ x, const float* __restrict__ y,
    const float* __restrict__ t0, const float* __restrict__ t1,
    const float* __restrict__ t2, const float* __restrict__ t3,
    const float* __restrict__ t4, float* __restrict__ out, int P) {
  int p = blockIdx.x * blockDim.x + threadIdx.x;
  if (p >= P) return;
  float xv = x[p];
  float yv = y[p];
  float o[8];
  float* orow = out + (size_t)p * 40u;
  sample_level_direct<64>(t0, xv, yv, o);
#pragma unroll
  for (int i = 0; i < 8; ++i) orow[0 + i] = o[i];
  sample_level_direct<128>(t1, xv, yv, o);
#pragma unroll
  for (int i = 0; i < 8; ++i) orow[8 + i] = o[i];
  sample_level_direct<256>(t2, xv, yv, o);
#pragma unroll
  for (int i = 0; i < 8; ++i) orow[16 + i] = o[i];
  sample_level_direct<512>(t3, xv, yv, o);
#pragma unroll
  for (int i = 0; i < 8; ++i) orow[24 + i] = o[i];
  sample_level_direct<1024>(t4, xv, yv, o);
#pragma unroll
  for (int i = 0; i < 8; ++i) orow[32 + i] = o[i];
}

extern "C" void kernel_launch(void* const* d_in, const int* in_sizes, int n_in,
                              void* d_out, int out_size, void* d_ws, size_t ws_size,
                              hipStream_t stream) {
  const float* x = (const float*)d_in[0];
  const float* y = (const float*)d_in[1];
  const float* tabs[5] = {(const float*)d_in[2], (const float*)d_in[3],
                          (const float*)d_in[4], (const float*)d_in[5],
                          (const float*)d_in[6]};
  float* out = (float*)d_out;
  const int P = in_sizes[0];

  const size_t offs[5] = {0, 8192, 40960, 172032, 696320};

  unsigned* cursor = (unsigned*)((char*)d_ws + WS_CURS);
  unsigned* ovf_cnt = (unsigned*)((char*)d_ws + WS_OVFC);
  int* ovf = (int*)((char*)d_ws + WS_OVF);
  float* slots = (float*)((char*)d_ws + WS_SLOT);

  if (ws_size >= WS_END_BF16 && P <= 1000448) {
    uint4* tb = (uint4*)((char*)d_ws + WS_TAB);
    (void)hipMemsetAsync((char*)d_ws, 0, WS_OVFC + 4, stream);
    scatter_bins_kernel<<<NSCAT, 512, 0, stream>>>(x, y, P, cursor, ovf_cnt,
                                                   ovf, slots);
    transform_kernel<<<10912, 256, 0, stream>>>(
        tabs[0], tabs[1], tabs[2], tabs[3], tabs[4], tb);
    sample_tile_bf16<<<1024, 256, 0, stream>>>(
        slots, cursor, tb + offs[0], tb + offs[1], tb + offs[2], tb + offs[3],
        tb + offs[4], out);
    sample_ovf_bf16<<<32, 256, 0, stream>>>(
        ovf_cnt, ovf, x, y, tb + offs[0], tb + offs[1], tb + offs[2],
        tb + offs[3], tb + offs[4], out);
  } else if (ws_size >= WS_END_I8 && P <= 1000448) {
    float* deq = (float*)((char*)d_ws + WS_DEQ);
    float* inv = (float*)((char*)d_ws + WS_INV);
    unsigned* partials = (unsigned*)((char*)d_ws + WS_PART);
    uint2* tb = (uint2*)((char*)d_ws + WS_TAB);
    (void)hipMemsetAsync((char*)d_ws, 0, WS_OVFC + 4, stream);
    absmax_scatter_kernel<<<NSCAT_I8 + 5456, 256, 0, stream>>>(
        tabs[0], tabs[1], tabs[2], tabs[3], tabs[4], partials, x, y, P, cursor,
        ovf_cnt, ovf, slots);
    finalize_scales_kernel<<<1, 256, 0, stream>>>(partials, deq, inv);
    quant_kernel<<<10912, 256, 0, stream>>>(
        tabs[0], tabs[1], tabs[2], tabs[3], tabs[4], tb, inv);
    sample_tile_i8<<<NGRP + 32, 256, 0, stream>>>(
        slots, cursor, ovf_cnt, ovf, x, y, tb + offs[0], tb + offs[1],
        tb + offs[2], tb + offs[3], tb + offs[4], deq, out, P);
  } else {
    sample_kernel_direct<<<(P + 255) / 256, 256, 0, stream>>>(
        x, y, tabs[0], tabs[1], tabs[2], tabs[3], tabs[4], out, P);
  }
}

// Round 22
// 165.678 us; speedup vs baseline: 1.0318x; 1.0318x over previous
//
#include <hip/hip_runtime.h>

// RES=[64,128,256,512,1024], NF=8, NC=2, P=1e6. out[p*40 + lvl*8 + c], fp32.
//
// Primary pipeline (bf16, scale-free — memset + 4 kernels):
//  memset(cursor+ovf_cnt)
//  K1a scatter_bins (64 x 512, 32KB LDS): LDS histogram -> ONE global
//      atomicAdd per (block,bin) -> placement writes 12B slots {xn,yn,perm}.
//  K1b transform (10912 x 256, no LDS): fp32 -> bf16 channel-last uint4/px.
//  K4  tile sample (4096 blocks = round-19 shape, best measured): L0-L3
//      staged in LDS (12KB; bound 670<=768 incl. adversarial fractions),
//      L4 PREFETCHED at loop top (8 uint4 loads issued before the LDS
//      section so their L2/HBM latency overlaps it — round-22 lever),
//      consumed after L3. Round-21 falsified 2x2-bin amortization (1024
//      blocks underfilled the machine, 110us).
//  K5  overflow kernel (32 blocks): identical-arithmetic global path.
// Fallbacks: int8 pipeline (ws>=37.9MB), else direct fp32.
//
// ws layout (bytes):
//   cursor[4096]@0  ovf_cnt@16384  deq[8]@16448  inv[8]@16480
//   partials[5456]@20480  ovf[131072]@65536
//   slots[4096*304]x12B@589824  tables@15532032
//   (bf16 tables end @60227584; int8 end @37879808)

#define WS_CURS 0
#define WS_OVFC 16384
#define WS_DEQ 16448
#define WS_INV 16480
#define WS_PART 20480
#define WS_OVF 65536
#define WS_SLOT 589824
#define WS_TAB 15532032
#define WS_END_BF16 60227584ull
#define WS_END_I8 37879808ull
#define NGRP 4096
#define CAP 304
#define OVF_CAP 131072
#define LDS_CAP 1600    // uint2 slots for i8 fallback (12.8KB)
#define LDS_CAP4 768    // uint4 slots for bf16 path (12KB), 1/64-tile L0-L3
#define NSCAT 64
#define NSCAT_I8 2048

typedef __attribute__((ext_vector_type(8))) unsigned short ushort8v;

__device__ __forceinline__ unsigned short f2bf(float f) {
  union { float f; unsigned u; } c; c.f = f;
  unsigned u = c.u;
  u += 0x7FFFu + ((u >> 16) & 1u);   // RNE
  return (unsigned short)(u >> 16);
}

__device__ __forceinline__ int bin_of(float xv, float yv) {
  int bx = min(max((int)(xv * 128.0f), 0), 127);
  int by = min(max((int)(yv * 128.0f), 0), 127);
  return (by >> 1) * 64 + (bx >> 1);
}

// legacy per-point scatter (int8 fallback path only)
__device__ __forceinline__ void scatter_one(
    const float* __restrict__ x, const float* __restrict__ y, int p,
    unsigned* __restrict__ cursor, unsigned* __restrict__ ovf_cnt,
    int* __restrict__ ovf, float* __restrict__ slots) {
  float xv = x[p], yv = y[p];
  int g = bin_of(xv, yv);
  unsigned s = atomicAdd(&cursor[g], 1u);
  if (s < CAP) {
    float* sp = slots + ((size_t)g * CAP + s) * 3u;
    sp[0] = xv * 2.0f - 1.0f;
    sp[1] = yv * 2.0f - 1.0f;
    sp[2] = __int_as_float(p);
  } else {
    unsigned o = atomicAdd(ovf_cnt, 1u);
    if (o < OVF_CAP) ovf[o] = p;
  }
}

// ==== K1a: LDS-aggregated counting scatter ====
__global__ __launch_bounds__(512) void scatter_bins_kernel(
    const float* __restrict__ x, const float* __restrict__ y, int P,
    unsigned* __restrict__ cursor, unsigned* __restrict__ ovf_cnt,
    int* __restrict__ ovf, float* __restrict__ slots) {
  __shared__ unsigned cnt[NGRP];    // 16 KB
  __shared__ unsigned base[NGRP];   // 16 KB
  int b = blockIdx.x;
  int tid = (int)threadIdx.x;
  int chunk = (P + NSCAT - 1) / NSCAT;
  int lo = b * chunk;
  int hi = min(lo + chunk, P);
  for (int i = tid; i < NGRP; i += 512) cnt[i] = 0u;
  __syncthreads();
  for (int p = lo + tid; p < hi; p += 512)
    atomicAdd(&cnt[bin_of(x[p], y[p])], 1u);
  __syncthreads();
  for (int g = tid; g < NGRP; g += 512) {
    unsigned c = cnt[g];
    base[g] = c ? atomicAdd(&cursor[g], c) : 0u;
  }
  __syncthreads();
  for (int i = tid; i < NGRP; i += 512) cnt[i] = 0u;
  __syncthreads();
  for (int p = lo + tid; p < hi; p += 512) {
    float xv = x[p], yv = y[p];
    int g = bin_of(xv, yv);
    unsigned r = atomicAdd(&cnt[g], 1u);
    unsigned idx = base[g] + r;
    if (idx < CAP) {
      float* sp = slots + ((size_t)g * CAP + idx) * 3u;
      sp[0] = xv * 2.0f - 1.0f;
      sp[1] = yv * 2.0f - 1.0f;
      sp[2] = __int_as_float(p);
    } else {
      unsigned o = atomicAdd(ovf_cnt, 1u);
      if (o < OVF_CAP) ovf[o] = p;
    }
  }
}

// ==== K1b: transform (no LDS -> full streaming occupancy) ====
__global__ __launch_bounds__(256) void transform_kernel(
    const float* __restrict__ s0, const float* __restrict__ s1,
    const float* __restrict__ s2, const float* __restrict__ s3,
    const float* __restrict__ s4, uint4* __restrict__ tb) {
  int b = blockIdx.x;
  const float* src; int HW; int lb; size_t toff;
  if (b < 32)        { src = s0; HW = 4096;    lb = 0;    toff = 0; }
  else if (b < 160)  { src = s1; HW = 16384;   lb = 32;   toff = 8192; }
  else if (b < 672)  { src = s2; HW = 65536;   lb = 160;  toff = 40960; }
  else if (b < 2720) { src = s3; HW = 262144;  lb = 672;  toff = 172032; }
  else               { src = s4; HW = 1048576; lb = 2720; toff = 696320; }
  int i = (b - lb) * 256 + (int)threadIdx.x;
  int cell = i / HW;
  int pix = i - cell * HW;
  const float* s = src + (size_t)cell * 8u * (size_t)HW + (size_t)pix;
  ushort8v v;
#pragma unroll
  for (int ch = 0; ch < 8; ++ch) v[ch] = f2bf(s[(size_t)ch * HW]);
  ((ushort8v*)tb)[toff + (size_t)i] = v;
}

// ==== shared window machinery ====
struct Win { int ixmin, iymin, ww, wh, base; };

template <int W>
__device__ __forceinline__ Win mkwin(float xlo, float xhi, float ylo, float yhi,
                                     int base) {
  const float s = (float)(W - 1);
  Win w;
  w.ixmin = max(0, (int)floorf(xlo * s) - 1);
  int ixmax = min(W - 1, (int)floorf(xhi * s + 0.5f) + 2);
  w.iymin = max(0, (int)floorf(ylo * s) - 1);
  int iymax = min(W - 1, (int)floorf(yhi * s + 0.5f) + 2);
  w.ww = ixmax - w.ixmin + 1;
  w.wh = iymax - w.iymin + 1;
  w.base = base;
  return w;
}

__device__ __forceinline__ void store8(float* __restrict__ o,
                                       const float* __restrict__ r) {
  ((float4*)o)[0] = make_float4(r[0], r[1], r[2], r[3]);
  ((float4*)o)[1] = make_float4(r[4], r[5], r[6], r[7]);
}

// ==== bf16 path ====
template <int W>
__device__ __forceinline__ void stage_bf16(uint4* __restrict__ lds, const Win& w,
                                           const uint4* __restrict__ t) {
  int n = w.ww * w.wh;
  for (int j = (int)threadIdx.x; j < 2 * n; j += 256) {
    int cell = j >= n;
    int jj = cell ? j - n : j;
    int r = jj / w.ww;
    int c = jj - r * w.ww;
    lds[w.base + j] = t[cell * W * W + (w.iymin + r) * W + (w.ixmin + c)];
  }
}

__device__ __forceinline__ void fma_bf(uint4 v, float w, float* __restrict__ acc) {
  acc[0] = fmaf(__uint_as_float(v.x << 16), w, acc[0]);
  acc[1] = fmaf(__uint_as_float(v.x & 0xFFFF0000u), w, acc[1]);
  acc[2] = fmaf(__uint_as_float(v.y << 16), w, acc[2]);
  acc[3] = fmaf(__uint_as_float(v.y & 0xFFFF0000u), w, acc[3]);
  acc[4] = fmaf(__uint_as_float(v.z << 16), w, acc[4]);
  acc[5] = fmaf(__uint_as_float(v.z & 0xFFFF0000u), w, acc[5]);
  acc[6] = fmaf(__uint_as_float(v.w << 16), w, acc[6]);
  acc[7] = fmaf(__uint_as_float(v.w & 0xFFFF0000u), w, acc[7]);
}

template <int W>
__device__ __forceinline__ void sample_bf_lds(const uint4* __restrict__ lds,
                                              const Win& w, float xn, float yn,
                                              float* __restrict__ res) {
  const float s = (float)(W - 1);
  float acc[8];
#pragma unroll
  for (int i = 0; i < 8; ++i) acc[i] = 0.0f;
#pragma unroll
  for (int cell = 0; cell < 2; ++cell) {
    const float off = 0.5f * (float)cell;
    float ix = (xn + 1.0f) * 0.5f * s + off;
    float iy = (yn + 1.0f) * 0.5f * s + off;
    float xf = floorf(ix), yf = floorf(iy);
    float wx = ix - xf, wy = iy - yf;
    int x0 = min(max((int)xf, 0), W - 1);
    int y0 = min(max((int)yf, 0), W - 1);
    int x1 = min(x0 + 1, W - 1);
    int y1 = min(y0 + 1, W - 1);
    int cb = w.base + cell * (w.ww * w.wh) - w.ixmin;
    int r0 = cb + (y0 - w.iymin) * w.ww;
    int r1 = cb + (y1 - w.iymin) * w.ww;
    uint4 c00 = lds[r0 + x0], c01 = lds[r0 + x1];
    uint4 c10 = lds[r1 + x0], c11 = lds[r1 + x1];
    float w00 = (1.0f - wx) * (1.0f - wy);
    float w01 = wx * (1.0f - wy);
    float w10 = (1.0f - wx) * wy;
    float w11 = wx * wy;
    fma_bf(c00, w00, acc);
    fma_bf(c01, w01, acc);
    fma_bf(c10, w10, acc);
    fma_bf(c11, w11, acc);
  }
#pragma unroll
  for (int i = 0; i < 8; ++i) res[i] = acc[i];
}

template <int W>
__device__ __forceinline__ void sample_bf_glob(const uint4* __restrict__ t,
                                               float xn, float yn,
                                               float* __restrict__ res) {
  const float s = (float)(W - 1);
  float acc[8];
#pragma unroll
  for (int i = 0; i < 8; ++i) acc[i] = 0.0f;
#pragma unroll
  for (int cell = 0; cell < 2; ++cell) {
    const float off = 0.5f * (float)cell;
    float ix = (xn + 1.0f) * 0.5f * s + off;
    float iy = (yn + 1.0f) * 0.5f * s + off;
    float xf = floorf(ix), yf = floorf(iy);
    float wx = ix - xf, wy = iy - yf;
    int x0 = min(max((int)xf, 0), W - 1);
    int y0 = min(max((int)yf, 0), W - 1);
    int x1 = min(x0 + 1, W - 1);
    int y1 = min(y0 + 1, W - 1);
    const uint4* b = t + cell * W * W;
    uint4 c00 = b[y0 * W + x0], c01 = b[y0 * W + x1];
    uint4 c10 = b[y1 * W + x0], c11 = b[y1 * W + x1];
    float w00 = (1.0f - wx) * (1.0f - wy);
    float w01 = wx * (1.0f - wy);
    float w10 = (1.0f - wx) * wy;
    float w11 = wx * wy;
    fma_bf(c00, w00, acc);
    fma_bf(c01, w01, acc);
    fma_bf(c10, w10, acc);
    fma_bf(c11, w11, acc);
  }
#pragma unroll
  for (int i = 0; i < 8; ++i) res[i] = acc[i];
}

// L4 prefetch: issue the 8 corner loads early so their latency overlaps the
// LDS-sampling section; consume after L3.
struct L4Pre {
  uint4 c[8];
  float wx0, wy0, wx1, wy1;
};

__device__ __forceinline__ L4Pre l4_prefetch(const uint4* __restrict__ t,
                                             float xn, float yn) {
  L4Pre p;
  const float s = 1023.0f;
#pragma unroll
  for (int cell = 0; cell < 2; ++cell) {
    const float off = 0.5f * (float)cell;
    float ix = (xn + 1.0f) * 0.5f * s + off;
    float iy = (yn + 1.0f) * 0.5f * s + off;
    float xf = floorf(ix), yf = floorf(iy);
    float wx = ix - xf, wy = iy - yf;
    int x0 = min(max((int)xf, 0), 1023);
    int y0 = min(max((int)yf, 0), 1023);
    int x1 = min(x0 + 1, 1023);
    int y1 = min(y0 + 1, 1023);
    const uint4* b = t + cell * 1024 * 1024;
    p.c[cell * 4 + 0] = b[y0 * 1024 + x0];
    p.c[cell * 4 + 1] = b[y0 * 1024 + x1];
    p.c[cell * 4 + 2] = b[y1 * 1024 + x0];
    p.c[cell * 4 + 3] = b[y1 * 1024 + x1];
    if (cell == 0) { p.wx0 = wx; p.wy0 = wy; }
    else           { p.wx1 = wx; p.wy1 = wy; }
  }
  return p;
}

__device__ __forceinline__ void l4_consume(const L4Pre& p,
                                           float* __restrict__ res) {
  float acc[8];
#pragma unroll
  for (int i = 0; i < 8; ++i) acc[i] = 0.0f;
  {
    float w00 = (1.0f - p.wx0) * (1.0f - p.wy0);
    float w01 = p.wx0 * (1.0f - p.wy0);
    float w10 = (1.0f - p.wx0) * p.wy0;
    float w11 = p.wx0 * p.wy0;
    fma_bf(p.c[0], w00, acc);
    fma_bf(p.c[1], w01, acc);
    fma_bf(p.c[2], w10, acc);
    fma_bf(p.c[3], w11, acc);
  }
  {
    float w00 = (1.0f - p.wx1) * (1.0f - p.wy1);
    float w01 = p.wx1 * (1.0f - p.wy1);
    float w10 = (1.0f - p.wx1) * p.wy1;
    float w11 = p.wx1 * p.wy1;
    fma_bf(p.c[4], w00, acc);
    fma_bf(p.c[5], w01, acc);
    fma_bf(p.c[6], w10, acc);
    fma_bf(p.c[7], w11, acc);
  }
#pragma unroll
  for (int i = 0; i < 8; ++i) res[i] = acc[i];
}

// K4: tile sample — one block per bin (round-19 shape), L4 prefetched.
__global__ __launch_bounds__(256) void sample_tile_bf16(
    const float* __restrict__ slots, const unsigned* __restrict__ cursor,
    const uint4* __restrict__ t0, const uint4* __restrict__ t1,
    const uint4* __restrict__ t2, const uint4* __restrict__ t3,
    const uint4* __restrict__ t4, float* __restrict__ out) {
  __shared__ uint4 lds[LDS_CAP4];
  int g = blockIdx.x;
  int cnt = min((int)cursor[g], CAP);
  if (cnt == 0) return;

  int gx = g & 63, gy = g >> 6;
  float xlo = (float)gx * (1.0f / 64.0f);
  float xhi = (float)(gx + 1) * (1.0f / 64.0f);
  float ylo = (float)gy * (1.0f / 64.0f);
  float yhi = (float)(gy + 1) * (1.0f / 64.0f);

  // L0-L3 windows; worst case <= 670 < 768 (adversarial fractions included).
  Win w0 = mkwin<64>(xlo, xhi, ylo, yhi, 0);
  Win w1 = mkwin<128>(xlo, xhi, ylo, yhi, w0.base + 2 * w0.ww * w0.wh);
  Win w2 = mkwin<256>(xlo, xhi, ylo, yhi, w1.base + 2 * w1.ww * w1.wh);
  Win w3 = mkwin<512>(xlo, xhi, ylo, yhi, w2.base + 2 * w2.ww * w2.wh);

  stage_bf16<64>(lds, w0, t0);
  stage_bf16<128>(lds, w1, t1);
  stage_bf16<256>(lds, w2, t2);
  stage_bf16<512>(lds, w3, t3);
  __syncthreads();

  const float* gs = slots + (size_t)g * CAP * 3u;
  for (int i = (int)threadIdx.x; i < cnt; i += 256) {
    const float* sp = gs + (size_t)i * 3u;
    float xn = sp[0], yn = sp[1];
    float* orow = out + (size_t)__float_as_int(sp[2]) * 40u;
    L4Pre pre = l4_prefetch(t4, xn, yn);       // loads in flight over LDS work
    float res[8];
    sample_bf_lds<64>(lds, w0, xn, yn, res);   store8(orow + 0, res);
    sample_bf_lds<128>(lds, w1, xn, yn, res);  store8(orow + 8, res);
    sample_bf_lds<256>(lds, w2, xn, yn, res);  store8(orow + 16, res);
    sample_bf_lds<512>(lds, w3, xn, yn, res);  store8(orow + 24, res);
    l4_consume(pre, res);                      store8(orow + 32, res);
  }
}

// K5: overflow stragglers (expected 0) — identical arithmetic.
__global__ __launch_bounds__(256) void sample_ovf_bf16(
    const unsigned* __restrict__ ovf_cnt, const int* __restrict__ ovf,
    const float* __restrict__ x, const float* __restrict__ y,
    const uint4* __restrict__ t0, const uint4* __restrict__ t1,
    const uint4* __restrict__ t2, const uint4* __restrict__ t3,
    const uint4* __restrict__ t4, float* __restrict__ out) {
  int n = min((int)*ovf_cnt, OVF_CAP);
  int stride = gridDim.x * 256;
  for (int i = blockIdx.x * 256 + (int)threadIdx.x; i < n; i += stride) {
    int p = ovf[i];
    float xn = x[p] * 2.0f - 1.0f;
    float yn = y[p] * 2.0f - 1.0f;
    float* orow = out + (size_t)p * 40u;
    float res[8];
    sample_bf_glob<64>(t0, xn, yn, res);   store8(orow + 0, res);
    sample_bf_glob<128>(t1, xn, yn, res);  store8(orow + 8, res);
    sample_bf_glob<256>(t2, xn, yn, res);  store8(orow + 16, res);
    sample_bf_glob<512>(t3, xn, yn, res);  store8(orow + 24, res);
    sample_bf_glob<1024>(t4, xn, yn, res); store8(orow + 32, res);
  }
}

// ==== int8 fallback path ====
__global__ __launch_bounds__(256) void absmax_scatter_kernel(
    const float* __restrict__ s0, const float* __restrict__ s1,
    const float* __restrict__ s2, const float* __restrict__ s3,
    const float* __restrict__ s4, unsigned* __restrict__ partials,
    const float* __restrict__ x, const float* __restrict__ y, int P,
    unsigned* __restrict__ cursor, unsigned* __restrict__ ovf_cnt,
    int* __restrict__ ovf, float* __restrict__ slots) {
  int b = blockIdx.x;
  if (b < NSCAT_I8) {
    int stride = NSCAT_I8 * 256;
    for (int p = b * 256 + (int)threadIdx.x; p < P; p += stride)
      scatter_one(x, y, p, cursor, ovf_cnt, ovf, slots);
    return;
  }
  int bb = b - NSCAT_I8;
  __shared__ unsigned red[4];
  const float* src; int n4; int lb; int nb;
  if (bb < 16)        { src = s0; n4 = 16384;   lb = 0;    nb = 16; }
  else if (bb < 80)   { src = s1; n4 = 65536;   lb = 16;   nb = 64; }
  else if (bb < 336)  { src = s2; n4 = 262144;  lb = 80;   nb = 256; }
  else if (bb < 1360) { src = s3; n4 = 1048576; lb = 336;  nb = 1024; }
  else                { src = s4; n4 = 4194304; lb = 1360; nb = 4096; }
  int local = bb - lb;
  unsigned m = 0;
  for (int k = local * 256 + threadIdx.x; k < n4; k += nb * 256) {
    float4 v = ((const float4*)src)[k];
    unsigned a = __float_as_uint(v.x) & 0x7FFFFFFFu;
    unsigned c = __float_as_uint(v.y) & 0x7FFFFFFFu;
    unsigned d = __float_as_uint(v.z) & 0x7FFFFFFFu;
    unsigned e = __float_as_uint(v.w) & 0x7FFFFFFFu;
    m = max(m, max(max(a, c), max(d, e)));
  }
#pragma unroll
  for (int off = 32; off; off >>= 1)
    m = max(m, (unsigned)__shfl_xor((int)m, off));
  if ((threadIdx.x & 63) == 0) red[threadIdx.x >> 6] = m;
  __syncthreads();
  if (threadIdx.x == 0)
    partials[bb] = max(max(red[0], red[1]), max(red[2], red[3]));
}

__global__ __launch_bounds__(256) void finalize_scales_kernel(
    const unsigned* __restrict__ partials, float* __restrict__ deq,
    float* __restrict__ inv) {
  __shared__ unsigned red[4];
  int t = (int)threadIdx.x;
  const int lo[5] = {0, 16, 80, 336, 1360};
  const int hi[5] = {16, 80, 336, 1360, 5456};
  for (int l = 0; l < 5; ++l) {
    unsigned m = 0;
    for (int i = lo[l] + t; i < hi[l]; i += 256) m = max(m, partials[i]);
#pragma unroll
    for (int off = 32; off; off >>= 1)
      m = max(m, (unsigned)__shfl_xor((int)m, off));
    if ((t & 63) == 0) red[t >> 6] = m;
    __syncthreads();
    if (t == 0) {
      unsigned r = max(max(red[0], red[1]), max(red[2], red[3]));
      float s = __uint_as_float(r);
      if (!(s > 0.0f)) s = 1e-20f;
      deq[l] = s / 127.0f;
      inv[l] = 127.0f / s;
    }
    __syncthreads();
  }
}

__global__ __launch_bounds__(256) void quant_kernel(
    const float* __restrict__ s0, const float* __restrict__ s1,
    const float* __restrict__ s2, const float* __restrict__ s3,
    const float* __restrict__ s4, uint2* __restrict__ tb,
    const float* __restrict__ invp) {
  int b = blockIdx.x;
  const float* src; int HW; int lb; int l; size_t toff;
  if (b < 32)        { src = s0; HW = 4096;    lb = 0;    l = 0; toff = 0; }
  else if (b < 160)  { src = s1; HW = 16384;   lb = 32;   l = 1; toff = 8192; }
  else if (b < 672)  { src = s2; HW = 65536;   lb = 160;  l = 2; toff = 40960; }
  else if (b < 2720) { src = s3; HW = 262144;  lb = 672;  l = 3; toff = 172032; }
  else               { src = s4; HW = 1048576; lb = 2720; l = 4; toff = 696320; }
  int i = (b - lb) * 256 + (int)threadIdx.x;
  float sc = invp[l];
  int cell = i / HW;
  int pix = i - cell * HW;
  const float* s = src + (size_t)cell * 8u * (size_t)HW + (size_t)pix;
  unsigned lov = 0, hiv = 0;
#pragma unroll
  for (int c = 0; c < 4; ++c) {
    int q = (int)rintf(s[(size_t)c * HW] * sc);
    q = min(max(q, -127), 127);
    lov |= ((unsigned)(q & 0xFF)) << (8 * c);
  }
#pragma unroll
  for (int c = 0; c < 4; ++c) {
    int q = (int)rintf(s[(size_t)(c + 4) * HW] * sc);
    q = min(max(q, -127), 127);
    hiv |= ((unsigned)(q & 0xFF)) << (8 * c);
  }
  tb[toff + (size_t)i] = make_uint2(lov, hiv);
}

template <int W>
__device__ __forceinline__ void stage_i8(uint2* __restrict__ lds, const Win& w,
                                         const uint2* __restrict__ t) {
  int n = w.ww * w.wh;
  for (int i = (int)threadIdx.x; i < 2 * n; i += 256) {
    int cell = i >= n;
    int j = cell ? i - n : i;
    int r = j / w.ww;
    int c = j - r * w.ww;
    lds[w.base + i] = t[cell * W * W + (w.iymin + r) * W + (w.ixmin + c)];
  }
}

__device__ __forceinline__ void fma_i8(unsigned lo, unsigned hi, float w,
                                       float* __restrict__ acc) {
#pragma unroll
  for (int c = 0; c < 4; ++c)
    acc[c] = fmaf((float)(signed char)(lo >> (8 * c)), w, acc[c]);
#pragma unroll
  for (int c = 0; c < 4; ++c)
    acc[4 + c] = fmaf((float)(signed char)(hi >> (8 * c)), w, acc[4 + c]);
}

template <int W>
__device__ __forceinline__ void sample_i8(const uint2* __restrict__ lds,
                                          const Win& w, bool use_lds,
                                          const uint2* __restrict__ t,
                                          float xn, float yn, float deq,
                                          float* __restrict__ res) {
  const float s = (float)(W - 1);
  float acc[8];
#pragma unroll
  for (int i = 0; i < 8; ++i) acc[i] = 0.0f;
#pragma unroll
  for (int cell = 0; cell < 2; ++cell) {
    const float off = 0.5f * (float)cell;
    float ix = (xn + 1.0f) * 0.5f * s + off;
    float iy = (yn + 1.0f) * 0.5f * s + off;
    float xf = floorf(ix), yf = floorf(iy);
    float wx = ix - xf, wy = iy - yf;
    int x0 = min(max((int)xf, 0), W - 1);
    int y0 = min(max((int)yf, 0), W - 1);
    int x1 = min(x0 + 1, W - 1);
    int y1 = min(y0 + 1, W - 1);
    uint2 c00, c01, c10, c11;
    if (use_lds) {
      int cb = w.base + cell * (w.ww * w.wh) - w.ixmin;
      int r0 = cb + (y0 - w.iymin) * w.ww;
      int r1 = cb + (y1 - w.iymin) * w.ww;
      c00 = lds[r0 + x0]; c01 = lds[r0 + x1];
      c10 = lds[r1 + x0]; c11 = lds[r1 + x1];
    } else {
      const uint2* b = t + cell * W * W;
      c00 = b[y0 * W + x0]; c01 = b[y0 * W + x1];
      c10 = b[y1 * W + x0]; c11 = b[y1 * W + x1];
    }
    float w00 = (1.0f - wx) * (1.0f - wy);
    float w01 = wx * (1.0f - wy);
    float w10 = (1.0f - wx) * wy;
    float w11 = wx * wy;
    fma_i8(c00.x, c00.y, w00, acc);
    fma_i8(c01.x, c01.y, w01, acc);
    fma_i8(c10.x, c10.y, w10, acc);
    fma_i8(c11.x, c11.y, w11, acc);
  }
#pragma unroll
  for (int i = 0; i < 8; ++i) res[i] = acc[i] * deq;
}

__global__ __launch_bounds__(256) void sample_tile_i8(
    const float* __restrict__ slots, const unsigned* __restrict__ cursor,
    const unsigned* __restrict__ ovf_cnt, const int* __restrict__ ovf,
    const float* __restrict__ x, const float* __restrict__ y,
    const uint2* __restrict__ t0, const uint2* __restrict__ t1,
    const uint2* __restrict__ t2, const uint2* __restrict__ t3,
    const uint2* __restrict__ t4, const float* __restrict__ deqs,
    float* __restrict__ out, int P) {
  __shared__ uint2 lds[LDS_CAP];
  int g = blockIdx.x;
  float d0 = deqs[0], d1 = deqs[1], d2 = deqs[2], d3 = deqs[3], d4 = deqs[4];
  Win wdum = {0, 0, 1, 1, 0};

  if (g >= NGRP) {
    int n = min((int)*ovf_cnt, OVF_CAP);
    int stride = (gridDim.x - NGRP) * 256;
    for (int i = (g - NGRP) * 256 + (int)threadIdx.x; i < n; i += stride) {
      int p = ovf[i];
      float xn = x[p] * 2.0f - 1.0f;
      float yn = y[p] * 2.0f - 1.0f;
      float* orow = out + (size_t)p * 40u;
      float res[8];
      sample_i8<64>(lds, wdum, false, t0, xn, yn, d0, res);   store8(orow + 0, res);
      sample_i8<128>(lds, wdum, false, t1, xn, yn, d1, res);  store8(orow + 8, res);
      sample_i8<256>(lds, wdum, false, t2, xn, yn, d2, res);  store8(orow + 16, res);
      sample_i8<512>(lds, wdum, false, t3, xn, yn, d3, res);  store8(orow + 24, res);
      sample_i8<1024>(lds, wdum, false, t4, xn, yn, d4, res); store8(orow + 32, res);
    }
    return;
  }

  int cnt = min((int)cursor[g], CAP);
  if (cnt == 0) return;

  int gx = g & 63, gy = g >> 6;
  float xlo = (float)gx * (1.0f / 64.0f);
  float xhi = (float)(gx + 1) * (1.0f / 64.0f);
  float ylo = (float)gy * (1.0f / 64.0f);
  float yhi = (float)(gy + 1) * (1.0f / 64.0f);

  Win w0 = mkwin<64>(xlo, xhi, ylo, yhi, 0);
  Win w1 = mkwin<128>(xlo, xhi, ylo, yhi, w0.base + 2 * w0.ww * w0.wh);
  Win w2 = mkwin<256>(xlo, xhi, ylo, yhi, w1.base + 2 * w1.ww * w1.wh);
  Win w3 = mkwin<512>(xlo, xhi, ylo, yhi, w2.base + 2 * w2.ww * w2.wh);
  Win w4 = mkwin<1024>(xlo, xhi, ylo, yhi, w3.base + 2 * w3.ww * w3.wh);
  int total = w4.base + 2 * w4.ww * w4.wh;
  bool use_lds = (total <= LDS_CAP);

  if (use_lds) {
    stage_i8<64>(lds, w0, t0);
    stage_i8<128>(lds, w1, t1);
    stage_i8<256>(lds, w2, t2);
    stage_i8<512>(lds, w3, t3);
    stage_i8<1024>(lds, w4, t4);
    __syncthreads();
  }

  const float* gs = slots + (size_t)g * CAP * 3u;
  for (int i = (int)threadIdx.x; i < cnt; i += 256) {
    const float* sp = gs + (size_t)i * 3u;
    float xn = sp[0], yn = sp[1];
    int q = __float_as_int(sp[2]);
    float* orow = out + (size_t)q * 40u;
    float res[8];
    sample_i8<64>(lds, w0, use_lds, t0, xn, yn, d0, res);   store8(orow + 0, res);
    sample_i8<128>(lds, w1, use_lds, t1, xn, yn, d1, res);  store8(orow + 8, res);
    sample_i8<256>(lds, w2, use_lds, t2, xn, yn, d2, res);  store8(orow + 16, res);
    sample_i8<512>(lds, w3, use_lds, t3, xn, yn, d3, res);  store8(orow + 24, res);
    sample_i8<1024>(lds, w4, use_lds, t4, xn, yn, d4, res); store8(orow + 32, res);
  }
}

// ==== tiny-ws fallback: direct fp32 ====
template <int W>
__device__ __forceinline__ void sample_level_direct(
    const float* __restrict__ t, float xv, float yv, float* __restrict__ o) {
  float acc[8];
#pragma unroll
  for (int i = 0; i < 8; ++i) acc[i] = 0.0f;
  float xn = xv * 2.0f - 1.0f;
  float yn = yv * 2.0f - 1.0f;
#pragma unroll
  for (int cell = 0; cell < 2; ++cell) {
    const float off = 0.5f * (float)cell;
    float ix = (xn + 1.0f) * 0.5f * (float)(W - 1) + off;
    float iy = (yn + 1.0f) * 0.5f * (float)(W - 1) + off;
    float x0f = floorf(ix), y0f = floorf(iy);
    float wx = ix - x0f, wy = iy - y0f;
    int x0 = (int)x0f; x0 = min(max(x0, 0), W - 1);
    int y0 = (int)y0f; y0 = min(max(y0, 0), W - 1);
    int x1 = min(x0 + 1, W - 1);
    int y1 = min(y0 + 1, W - 1);
    float w00 = (1.0f - wx) * (1.0f - wy);
    float w01 = wx * (1.0f - wy);
    float w10 = (1.0f - wx) * wy;
    float w11 = wx * wy;
    size_t i00 = (size_t)y0 * W + x0;
    size_t i01 = (size_t)y0 * W + x1;
    size_t i10 = (size_t)y1 * W + x0;
    size_t i11 = (size_t)y1 * W + x1;
#pragma unroll
    for (int c = 0; c < 8; ++c) {
      const float* pc = t + (size_t)cell * 8u * (size_t)W * (size_t)W +
                        (size_t)c * (size_t)W * (size_t)W;
      acc[c] += pc[i00] * w00 + pc[i01] * w01 + pc[i10] * w10 + pc[i11] * w11;
    }
  }
#pragma unroll
  for (int i = 0; i < 8; ++i) o[i] = acc[i];
}

__global__ __launch_bounds__(256) void sample_kernel_direct(
    const float* __restrict__ x, const float* __restrict__ y,
    const float* __restrict__ t0, const float* __restrict__ t1,
    const float* __restrict__ t2, const float* __restrict__ t3,
    const float* __restrict__ t4, float* __restrict__ out, int P) {
  int p = blockIdx.x * blockDim.x + threadIdx.x;
  if (p >= P) return;
  float xv = x[p];
  float yv = y[p];
  float o[8];
  float* orow = out + (size_t)p * 40u;
  sample_level_direct<64>(t0, xv, yv, o);
#pragma unroll
  for (int i = 0; i < 8; ++i) orow[0 + i] = o[i];
  sample_level_direct<128>(t1, xv, yv, o);
#pragma unroll
  for (int i = 0; i < 8; ++i) orow[8 + i] = o[i];
  sample_level_direct<256>(t2, xv, yv, o);
#pragma unroll
  for (int i = 0; i < 8; ++i) orow[16 + i] = o[i];
  sample_level_direct<512>(t3, xv, yv, o);
#pragma unroll
  for (int i = 0; i < 8; ++i) orow[24 + i] = o[i];
  sample_level_direct<1024>(t4, xv, yv, o);
#pragma unroll
  for (int i = 0; i < 8; ++i) orow[32 + i] = o[i];
}

extern "C" void kernel_launch(void* const* d_in, const int* in_sizes, int n_in,
                              void* d_out, int out_size, void* d_ws, size_t ws_size,
                              hipStream_t stream) {
  const float* x = (const float*)d_in[0];
  const float* y = (const float*)d_in[1];
  const float* tabs[5] = {(const float*)d_in[2], (const float*)d_in[3],
                          (const float*)d_in[4], (const float*)d_in[5],
                          (const float*)d_in[6]};
  float* out = (float*)d_out;
  const int P = in_sizes[0];

  const size_t offs[5] = {0, 8192, 40960, 172032, 696320};

  unsigned* cursor = (unsigned*)((char*)d_ws + WS_CURS);
  unsigned* ovf_cnt = (unsigned*)((char*)d_ws + WS_OVFC);
  int* ovf = (int*)((char*)d_ws + WS_OVF);
  float* slots = (float*)((char*)d_ws + WS_SLOT);

  if (ws_size >= WS_END_BF16 && P <= 1000448) {
    uint4* tb = (uint4*)((char*)d_ws + WS_TAB);
    (void)hipMemsetAsync((char*)d_ws, 0, WS_OVFC + 4, stream);
    scatter_bins_kernel<<<NSCAT, 512, 0, stream>>>(x, y, P, cursor, ovf_cnt,
                                                   ovf, slots);
    transform_kernel<<<10912, 256, 0, stream>>>(
        tabs[0], tabs[1], tabs[2], tabs[3], tabs[4], tb);
    sample_tile_bf16<<<NGRP, 256, 0, stream>>>(
        slots, cursor, tb + offs[0], tb + offs[1], tb + offs[2], tb + offs[3],
        tb + offs[4], out);
    sample_ovf_bf16<<<32, 256, 0, stream>>>(
        ovf_cnt, ovf, x, y, tb + offs[0], tb + offs[1], tb + offs[2],
        tb + offs[3], tb + offs[4], out);
  } else if (ws_size >= WS_END_I8 && P <= 1000448) {
    float* deq = (float*)((char*)d_ws + WS_DEQ);
    float* inv = (float*)((char*)d_ws + WS_INV);
    unsigned* partials = (unsigned*)((char*)d_ws + WS_PART);
    uint2* tb = (uint2*)((char*)d_ws + WS_TAB);
    (void)hipMemsetAsync((char*)d_ws, 0, WS_OVFC + 4, stream);
    absmax_scatter_kernel<<<NSCAT_I8 + 5456, 256, 0, stream>>>(
        tabs[0], tabs[1], tabs[2], tabs[3], tabs[4], partials, x, y, P, cursor,
        ovf_cnt, ovf, slots);
    finalize_scales_kernel<<<1, 256, 0, stream>>>(partials, deq, inv);
    quant_kernel<<<10912, 256, 0, stream>>>(
        tabs[0], tabs[1], tabs[2], tabs[3], tabs[4], tb, inv);
    sample_tile_i8<<<NGRP + 32, 256, 0, stream>>>(
        slots, cursor, ovf_cnt, ovf, x, y, tb + offs[0], tb + offs[1],
        tb + offs[2], tb + offs[3], tb + offs[4], deq, out, P);
  } else {
    sample_kernel_direct<<<(P + 255) / 256, 256, 0, stream>>>(
        x, y, tabs[0], tabs[1], tabs[2], tabs[3], tabs[4], out, P);
  }
}

// Round 23
// 161.377 us; speedup vs baseline: 1.0593x; 1.0267x over previous
//
#include <hip/hip_runtime.h>

// RES=[64,128,256,512,1024], NF=8, NC=2, P=1e6. out[p*40 + lvl*8 + c], fp32.
//
// FINAL pipeline (bf16, scale-free — memset + 4 kernels), best measured:
//  memset(cursor+ovf_cnt)
//  K1a scatter_bins (64 x 512, 32KB LDS): LDS histogram -> ONE global
//      atomicAdd per (block,bin) -> placement writes 12B slots {xn,yn,perm}.
//  K1b transform (10912 x 256, no LDS): fp32 -> bf16 channel-last uint4/px.
//  K4  tile sample (4096 blocks, plain launch_bounds(256)): L0-L3 staged in
//      LDS (12KB), L4 direct from bf16 global (L2/L3-resident).
//      Round-22 falsified L4 prefetch (+4us: VGPR 56->64, no overlap gain).
//      Sample kernel is at its structural floor (~97us across 7 configs):
//      10 divergent 16B stores/point (~130cy TA each) + 8 gathers + 40 LDS
//      reads; scattered 160B out-rows cap write BW ~2.4TB/s.
//  K5  overflow kernel (32 blocks): identical-arithmetic global path.
// Fallbacks: int8 pipeline (ws>=37.9MB), else direct fp32.
//
// ws layout (bytes):
//   cursor[4096]@0  ovf_cnt@16384  deq[8]@16448  inv[8]@16480
//   partials[5456]@20480  ovf[131072]@65536
//   slots[4096*304]x12B@589824  tables@15532032
//   (bf16 tables end @60227584; int8 end @37879808)

#define WS_CURS 0
#define WS_OVFC 16384
#define WS_DEQ 16448
#define WS_INV 16480
#define WS_PART 20480
#define WS_OVF 65536
#define WS_SLOT 589824
#define WS_TAB 15532032
#define WS_END_BF16 60227584ull
#define WS_END_I8 37879808ull
#define NGRP 4096
#define CAP 304
#define OVF_CAP 131072
#define LDS_CAP 1600    // uint2 slots for i8 fallback (12.8KB)
#define LDS_CAP4 768    // uint4 slots for bf16 path (12KB), 1/64-tile L0-L3
#define NSCAT 64
#define NSCAT_I8 2048

typedef __attribute__((ext_vector_type(8))) unsigned short ushort8v;

__device__ __forceinline__ unsigned short f2bf(float f) {
  union { float f; unsigned u; } c; c.f = f;
  unsigned u = c.u;
  u += 0x7FFFu + ((u >> 16) & 1u);   // RNE
  return (unsigned short)(u >> 16);
}

__device__ __forceinline__ int bin_of(float xv, float yv) {
  int bx = min(max((int)(xv * 128.0f), 0), 127);
  int by = min(max((int)(yv * 128.0f), 0), 127);
  return (by >> 1) * 64 + (bx >> 1);
}

// legacy per-point scatter (int8 fallback path only)
__device__ __forceinline__ void scatter_one(
    const float* __restrict__ x, const float* __restrict__ y, int p,
    unsigned* __restrict__ cursor, unsigned* __restrict__ ovf_cnt,
    int* __restrict__ ovf, float* __restrict__ slots) {
  float xv = x[p], yv = y[p];
  int g = bin_of(xv, yv);
  unsigned s = atomicAdd(&cursor[g], 1u);
  if (s < CAP) {
    float* sp = slots + ((size_t)g * CAP + s) * 3u;
    sp[0] = xv * 2.0f - 1.0f;
    sp[1] = yv * 2.0f - 1.0f;
    sp[2] = __int_as_float(p);
  } else {
    unsigned o = atomicAdd(ovf_cnt, 1u);
    if (o < OVF_CAP) ovf[o] = p;
  }
}

// ==== K1a: LDS-aggregated counting scatter ====
__global__ __launch_bounds__(512) void scatter_bins_kernel(
    const float* __restrict__ x, const float* __restrict__ y, int P,
    unsigned* __restrict__ cursor, unsigned* __restrict__ ovf_cnt,
    int* __restrict__ ovf, float* __restrict__ slots) {
  __shared__ unsigned cnt[NGRP];    // 16 KB
  __shared__ unsigned base[NGRP];   // 16 KB
  int b = blockIdx.x;
  int tid = (int)threadIdx.x;
  int chunk = (P + NSCAT - 1) / NSCAT;
  int lo = b * chunk;
  int hi = min(lo + chunk, P);
  for (int i = tid; i < NGRP; i += 512) cnt[i] = 0u;
  __syncthreads();
  for (int p = lo + tid; p < hi; p += 512)
    atomicAdd(&cnt[bin_of(x[p], y[p])], 1u);
  __syncthreads();
  for (int g = tid; g < NGRP; g += 512) {
    unsigned c = cnt[g];
    base[g] = c ? atomicAdd(&cursor[g], c) : 0u;
  }
  __syncthreads();
  for (int i = tid; i < NGRP; i += 512) cnt[i] = 0u;
  __syncthreads();
  for (int p = lo + tid; p < hi; p += 512) {
    float xv = x[p], yv = y[p];
    int g = bin_of(xv, yv);
    unsigned r = atomicAdd(&cnt[g], 1u);
    unsigned idx = base[g] + r;
    if (idx < CAP) {
      float* sp = slots + ((size_t)g * CAP + idx) * 3u;
      sp[0] = xv * 2.0f - 1.0f;
      sp[1] = yv * 2.0f - 1.0f;
      sp[2] = __int_as_float(p);
    } else {
      unsigned o = atomicAdd(ovf_cnt, 1u);
      if (o < OVF_CAP) ovf[o] = p;
    }
  }
}

// ==== K1b: transform (no LDS -> full streaming occupancy) ====
__global__ __launch_bounds__(256) void transform_kernel(
    const float* __restrict__ s0, const float* __restrict__ s1,
    const float* __restrict__ s2, const float* __restrict__ s3,
    const float* __restrict__ s4, uint4* __restrict__ tb) {
  int b = blockIdx.x;
  const float* src; int HW; int lb; size_t toff;
  if (b < 32)        { src = s0; HW = 4096;    lb = 0;    toff = 0; }
  else if (b < 160)  { src = s1; HW = 16384;   lb = 32;   toff = 8192; }
  else if (b < 672)  { src = s2; HW = 65536;   lb = 160;  toff = 40960; }
  else if (b < 2720) { src = s3; HW = 262144;  lb = 672;  toff = 172032; }
  else               { src = s4; HW = 1048576; lb = 2720; toff = 696320; }
  int i = (b - lb) * 256 + (int)threadIdx.x;
  int cell = i / HW;
  int pix = i - cell * HW;
  const float* s = src + (size_t)cell * 8u * (size_t)HW + (size_t)pix;
  ushort8v v;
#pragma unroll
  for (int ch = 0; ch < 8; ++ch) v[ch] = f2bf(s[(size_t)ch * HW]);
  ((ushort8v*)tb)[toff + (size_t)i] = v;
}

// ==== shared window machinery ====
struct Win { int ixmin, iymin, ww, wh, base; };

template <int W>
__device__ __forceinline__ Win mkwin(float xlo, float xhi, float ylo, float yhi,
                                     int base) {
  const float s = (float)(W - 1);
  Win w;
  w.ixmin = max(0, (int)floorf(xlo * s) - 1);
  int ixmax = min(W - 1, (int)floorf(xhi * s + 0.5f) + 2);
  w.iymin = max(0, (int)floorf(ylo * s) - 1);
  int iymax = min(W - 1, (int)floorf(yhi * s + 0.5f) + 2);
  w.ww = ixmax - w.ixmin + 1;
  w.wh = iymax - w.iymin + 1;
  w.base = base;
  return w;
}

__device__ __forceinline__ void store8(float* __restrict__ o,
                                       const float* __restrict__ r) {
  ((float4*)o)[0] = make_float4(r[0], r[1], r[2], r[3]);
  ((float4*)o)[1] = make_float4(r[4], r[5], r[6], r[7]);
}

// ==== bf16 path ====
template <int W>
__device__ __forceinline__ void stage_bf16(uint4* __restrict__ lds, const Win& w,
                                           const uint4* __restrict__ t) {
  int n = w.ww * w.wh;
  for (int j = (int)threadIdx.x; j < 2 * n; j += 256) {
    int cell = j >= n;
    int jj = cell ? j - n : j;
    int r = jj / w.ww;
    int c = jj - r * w.ww;
    lds[w.base + j] = t[cell * W * W + (w.iymin + r) * W + (w.ixmin + c)];
  }
}

__device__ __forceinline__ void fma_bf(uint4 v, float w, float* __restrict__ acc) {
  acc[0] = fmaf(__uint_as_float(v.x << 16), w, acc[0]);
  acc[1] = fmaf(__uint_as_float(v.x & 0xFFFF0000u), w, acc[1]);
  acc[2] = fmaf(__uint_as_float(v.y << 16), w, acc[2]);
  acc[3] = fmaf(__uint_as_float(v.y & 0xFFFF0000u), w, acc[3]);
  acc[4] = fmaf(__uint_as_float(v.z << 16), w, acc[4]);
  acc[5] = fmaf(__uint_as_float(v.z & 0xFFFF0000u), w, acc[5]);
  acc[6] = fmaf(__uint_as_float(v.w << 16), w, acc[6]);
  acc[7] = fmaf(__uint_as_float(v.w & 0xFFFF0000u), w, acc[7]);
}

template <int W>
__device__ __forceinline__ void sample_bf_lds(const uint4* __restrict__ lds,
                                              const Win& w, float xn, float yn,
                                              float* __restrict__ res) {
  const float s = (float)(W - 1);
  float acc[8];
#pragma unroll
  for (int i = 0; i < 8; ++i) acc[i] = 0.0f;
#pragma unroll
  for (int cell = 0; cell < 2; ++cell) {
    const float off = 0.5f * (float)cell;
    float ix = (xn + 1.0f) * 0.5f * s + off;
    float iy = (yn + 1.0f) * 0.5f * s + off;
    float xf = floorf(ix), yf = floorf(iy);
    float wx = ix - xf, wy = iy - yf;
    int x0 = min(max((int)xf, 0), W - 1);
    int y0 = min(max((int)yf, 0), W - 1);
    int x1 = min(x0 + 1, W - 1);
    int y1 = min(y0 + 1, W - 1);
    int cb = w.base + cell * (w.ww * w.wh) - w.ixmin;
    int r0 = cb + (y0 - w.iymin) * w.ww;
    int r1 = cb + (y1 - w.iymin) * w.ww;
    uint4 c00 = lds[r0 + x0], c01 = lds[r0 + x1];
    uint4 c10 = lds[r1 + x0], c11 = lds[r1 + x1];
    float w00 = (1.0f - wx) * (1.0f - wy);
    float w01 = wx * (1.0f - wy);
    float w10 = (1.0f - wx) * wy;
    float w11 = wx * wy;
    fma_bf(c00, w00, acc);
    fma_bf(c01, w01, acc);
    fma_bf(c10, w10, acc);
    fma_bf(c11, w11, acc);
  }
#pragma unroll
  for (int i = 0; i < 8; ++i) res[i] = acc[i];
}

template <int W>
__device__ __forceinline__ void sample_bf_glob(const uint4* __restrict__ t,
                                               float xn, float yn,
                                               float* __restrict__ res) {
  const float s = (float)(W - 1);
  float acc[8];
#pragma unroll
  for (int i = 0; i < 8; ++i) acc[i] = 0.0f;
#pragma unroll
  for (int cell = 0; cell < 2; ++cell) {
    const float off = 0.5f * (float)cell;
    float ix = (xn + 1.0f) * 0.5f * s + off;
    float iy = (yn + 1.0f) * 0.5f * s + off;
    float xf = floorf(ix), yf = floorf(iy);
    float wx = ix - xf, wy = iy - yf;
    int x0 = min(max((int)xf, 0), W - 1);
    int y0 = min(max((int)yf, 0), W - 1);
    int x1 = min(x0 + 1, W - 1);
    int y1 = min(y0 + 1, W - 1);
    const uint4* b = t + cell * W * W;
    uint4 c00 = b[y0 * W + x0], c01 = b[y0 * W + x1];
    uint4 c10 = b[y1 * W + x0], c11 = b[y1 * W + x1];
    float w00 = (1.0f - wx) * (1.0f - wy);
    float w01 = wx * (1.0f - wy);
    float w10 = (1.0f - wx) * wy;
    float w11 = wx * wy;
    fma_bf(c00, w00, acc);
    fma_bf(c01, w01, acc);
    fma_bf(c10, w10, acc);
    fma_bf(c11, w11, acc);
  }
#pragma unroll
  for (int i = 0; i < 8; ++i) res[i] = acc[i];
}

// K4: tile sample — one block per bin, L0-L3 LDS, L4 direct (best measured).
__global__ __launch_bounds__(256) void sample_tile_bf16(
    const float* __restrict__ slots, const unsigned* __restrict__ cursor,
    const uint4* __restrict__ t0, const uint4* __restrict__ t1,
    const uint4* __restrict__ t2, const uint4* __restrict__ t3,
    const uint4* __restrict__ t4, float* __restrict__ out) {
  __shared__ uint4 lds[LDS_CAP4];
  int g = blockIdx.x;
  int cnt = min((int)cursor[g], CAP);
  if (cnt == 0) return;

  int gx = g & 63, gy = g >> 6;
  float xlo = (float)gx * (1.0f / 64.0f);
  float xhi = (float)(gx + 1) * (1.0f / 64.0f);
  float ylo = (float)gy * (1.0f / 64.0f);
  float yhi = (float)(gy + 1) * (1.0f / 64.0f);

  // L0-L3 windows; worst case <= 670 < 768 (adversarial fractions included).
  Win w0 = mkwin<64>(xlo, xhi, ylo, yhi, 0);
  Win w1 = mkwin<128>(xlo, xhi, ylo, yhi, w0.base + 2 * w0.ww * w0.wh);
  Win w2 = mkwin<256>(xlo, xhi, ylo, yhi, w1.base + 2 * w1.ww * w1.wh);
  Win w3 = mkwin<512>(xlo, xhi, ylo, yhi, w2.base + 2 * w2.ww * w2.wh);

  stage_bf16<64>(lds, w0, t0);
  stage_bf16<128>(lds, w1, t1);
  stage_bf16<256>(lds, w2, t2);
  stage_bf16<512>(lds, w3, t3);
  __syncthreads();

  const float* gs = slots + (size_t)g * CAP * 3u;
  for (int i = (int)threadIdx.x; i < cnt; i += 256) {
    const float* sp = gs + (size_t)i * 3u;
    float xn = sp[0], yn = sp[1];
    float* orow = out + (size_t)__float_as_int(sp[2]) * 40u;
    float res[8];
    sample_bf_lds<64>(lds, w0, xn, yn, res);   store8(orow + 0, res);
    sample_bf_lds<128>(lds, w1, xn, yn, res);  store8(orow + 8, res);
    sample_bf_lds<256>(lds, w2, xn, yn, res);  store8(orow + 16, res);
    sample_bf_lds<512>(lds, w3, xn, yn, res);  store8(orow + 24, res);
    sample_bf_glob<1024>(t4, xn, yn, res);     store8(orow + 32, res);
  }
}

// K5: overflow stragglers (expected 0) — identical arithmetic.
__global__ __launch_bounds__(256) void sample_ovf_bf16(
    const unsigned* __restrict__ ovf_cnt, const int* __restrict__ ovf,
    const float* __restrict__ x, const float* __restrict__ y,
    const uint4* __restrict__ t0, const uint4* __restrict__ t1,
    const uint4* __restrict__ t2, const uint4* __restrict__ t3,
    const uint4* __restrict__ t4, float* __restrict__ out) {
  int n = min((int)*ovf_cnt, OVF_CAP);
  int stride = gridDim.x * 256;
  for (int i = blockIdx.x * 256 + (int)threadIdx.x; i < n; i += stride) {
    int p = ovf[i];
    float xn = x[p] * 2.0f - 1.0f;
    float yn = y[p] * 2.0f - 1.0f;
    float* orow = out + (size_t)p * 40u;
    float res[8];
    sample_bf_glob<64>(t0, xn, yn, res);   store8(orow + 0, res);
    sample_bf_glob<128>(t1, xn, yn, res);  store8(orow + 8, res);
    sample_bf_glob<256>(t2, xn, yn, res);  store8(orow + 16, res);
    sample_bf_glob<512>(t3, xn, yn, res);  store8(orow + 24, res);
    sample_bf_glob<1024>(t4, xn, yn, res); store8(orow + 32, res);
  }
}

// ==== int8 fallback path ====
__global__ __launch_bounds__(256) void absmax_scatter_kernel(
    const float* __restrict__ s0, const float* __restrict__ s1,
    const float* __restrict__ s2, const float* __restrict__ s3,
    const float* __restrict__ s4, unsigned* __restrict__ partials,
    const float* __restrict__ x, const float* __restrict__ y, int P,
    unsigned* __restrict__ cursor, unsigned* __restrict__ ovf_cnt,
    int* __restrict__ ovf, float* __restrict__ slots) {
  int b = blockIdx.x;
  if (b < NSCAT_I8) {
    int stride = NSCAT_I8 * 256;
    for (int p = b * 256 + (int)threadIdx.x; p < P; p += stride)
      scatter_one(x, y, p, cursor, ovf_cnt, ovf, slots);
    return;
  }
  int bb = b - NSCAT_I8;
  __shared__ unsigned red[4];
  const float* src; int n4; int lb; int nb;
  if (bb < 16)        { src = s0; n4 = 16384;   lb = 0;    nb = 16; }
  else if (bb < 80)   { src = s1; n4 = 65536;   lb = 16;   nb = 64; }
  else if (bb < 336)  { src = s2; n4 = 262144;  lb = 80;   nb = 256; }
  else if (bb < 1360) { src = s3; n4 = 1048576; lb = 336;  nb = 1024; }
  else                { src = s4; n4 = 4194304; lb = 1360; nb = 4096; }
  int local = bb - lb;
  unsigned m = 0;
  for (int k = local * 256 + threadIdx.x; k < n4; k += nb * 256) {
    float4 v = ((const float4*)src)[k];
    unsigned a = __float_as_uint(v.x) & 0x7FFFFFFFu;
    unsigned c = __float_as_uint(v.y) & 0x7FFFFFFFu;
    unsigned d = __float_as_uint(v.z) & 0x7FFFFFFFu;
    unsigned e = __float_as_uint(v.w) & 0x7FFFFFFFu;
    m = max(m, max(max(a, c), max(d, e)));
  }
#pragma unroll
  for (int off = 32; off; off >>= 1)
    m = max(m, (unsigned)__shfl_xor((int)m, off));
  if ((threadIdx.x & 63) == 0) red[threadIdx.x >> 6] = m;
  __syncthreads();
  if (threadIdx.x == 0)
    partials[bb] = max(max(red[0], red[1]), max(red[2], red[3]));
}

__global__ __launch_bounds__(256) void finalize_scales_kernel(
    const unsigned* __restrict__ partials, float* __restrict__ deq,
    float* __restrict__ inv) {
  __shared__ unsigned red[4];
  int t = (int)threadIdx.x;
  const int lo[5] = {0, 16, 80, 336, 1360};
  const int hi[5] = {16, 80, 336, 1360, 5456};
  for (int l = 0; l < 5; ++l) {
    unsigned m = 0;
    for (int i = lo[l] + t; i < hi[l]; i += 256) m = max(m, partials[i]);
#pragma unroll
    for (int off = 32; off; off >>= 1)
      m = max(m, (unsigned)__shfl_xor((int)m, off));
    if ((t & 63) == 0) red[t >> 6] = m;
    __syncthreads();
    if (t == 0) {
      unsigned r = max(max(red[0], red[1]), max(red[2], red[3]));
      float s = __uint_as_float(r);
      if (!(s > 0.0f)) s = 1e-20f;
      deq[l] = s / 127.0f;
      inv[l] = 127.0f / s;
    }
    __syncthreads();
  }
}

__global__ __launch_bounds__(256) void quant_kernel(
    const float* __restrict__ s0, const float* __restrict__ s1,
    const float* __restrict__ s2, const float* __restrict__ s3,
    const float* __restrict__ s4, uint2* __restrict__ tb,
    const float* __restrict__ invp) {
  int b = blockIdx.x;
  const float* src; int HW; int lb; int l; size_t toff;
  if (b < 32)        { src = s0; HW = 4096;    lb = 0;    l = 0; toff = 0; }
  else if (b < 160)  { src = s1; HW = 16384;   lb = 32;   l = 1; toff = 8192; }
  else if (b < 672)  { src = s2; HW = 65536;   lb = 160;  l = 2; toff = 40960; }
  else if (b < 2720) { src = s3; HW = 262144;  lb = 672;  l = 3; toff = 172032; }
  else               { src = s4; HW = 1048576; lb = 2720; l = 4; toff = 696320; }
  int i = (b - lb) * 256 + (int)threadIdx.x;
  float sc = invp[l];
  int cell = i / HW;
  int pix = i - cell * HW;
  const float* s = src + (size_t)cell * 8u * (size_t)HW + (size_t)pix;
  unsigned lov = 0, hiv = 0;
#pragma unroll
  for (int c = 0; c < 4; ++c) {
    int q = (int)rintf(s[(size_t)c * HW] * sc);
    q = min(max(q, -127), 127);
    lov |= ((unsigned)(q & 0xFF)) << (8 * c);
  }
#pragma unroll
  for (int c = 0; c < 4; ++c) {
    int q = (int)rintf(s[(size_t)(c + 4) * HW] * sc);
    q = min(max(q, -127), 127);
    hiv |= ((unsigned)(q & 0xFF)) << (8 * c);
  }
  tb[toff + (size_t)i] = make_uint2(lov, hiv);
}

template <int W>
__device__ __forceinline__ void stage_i8(uint2* __restrict__ lds, const Win& w,
                                         const uint2* __restrict__ t) {
  int n = w.ww * w.wh;
  for (int i = (int)threadIdx.x; i < 2 * n; i += 256) {
    int cell = i >= n;
    int j = cell ? i - n : i;
    int r = j / w.ww;
    int c = j - r * w.ww;
    lds[w.base + i] = t[cell * W * W + (w.iymin + r) * W + (w.ixmin + c)];
  }
}

__device__ __forceinline__ void fma_i8(unsigned lo, unsigned hi, float w,
                                       float* __restrict__ acc) {
#pragma unroll
  for (int c = 0; c < 4; ++c)
    acc[c] = fmaf((float)(signed char)(lo >> (8 * c)), w, acc[c]);
#pragma unroll
  for (int c = 0; c < 4; ++c)
    acc[4 + c] = fmaf((float)(signed char)(hi >> (8 * c)), w, acc[4 + c]);
}

template <int W>
__device__ __forceinline__ void sample_i8(const uint2* __restrict__ lds,
                                          const Win& w, bool use_lds,
                                          const uint2* __restrict__ t,
                                          float xn, float yn, float deq,
                                          float* __restrict__ res) {
  const float s = (float)(W - 1);
  float acc[8];
#pragma unroll
  for (int i = 0; i < 8; ++i) acc[i] = 0.0f;
#pragma unroll
  for (int cell = 0; cell < 2; ++cell) {
    const float off = 0.5f * (float)cell;
    float ix = (xn + 1.0f) * 0.5f * s + off;
    float iy = (yn + 1.0f) * 0.5f * s + off;
    float xf = floorf(ix), yf = floorf(iy);
    float wx = ix - xf, wy = iy - yf;
    int x0 = min(max((int)xf, 0), W - 1);
    int y0 = min(max((int)yf, 0), W - 1);
    int x1 = min(x0 + 1, W - 1);
    int y1 = min(y0 + 1, W - 1);
    uint2 c00, c01, c10, c11;
    if (use_lds) {
      int cb = w.base + cell * (w.ww * w.wh) - w.ixmin;
      int r0 = cb + (y0 - w.iymin) * w.ww;
      int r1 = cb + (y1 - w.iymin) * w.ww;
      c00 = lds[r0 + x0]; c01 = lds[r0 + x1];
      c10 = lds[r1 + x0]; c11 = lds[r1 + x1];
    } else {
      const uint2* b = t + cell * W * W;
      c00 = b[y0 * W + x0]; c01 = b[y0 * W + x1];
      c10 = b[y1 * W + x0]; c11 = b[y1 * W + x1];
    }
    float w00 = (1.0f - wx) * (1.0f - wy);
    float w01 = wx * (1.0f - wy);
    float w10 = (1.0f - wx) * wy;
    float w11 = wx * wy;
    fma_i8(c00.x, c00.y, w00, acc);
    fma_i8(c01.x, c01.y, w01, acc);
    fma_i8(c10.x, c10.y, w10, acc);
    fma_i8(c11.x, c11.y, w11, acc);
  }
#pragma unroll
  for (int i = 0; i < 8; ++i) res[i] = acc[i] * deq;
}

__global__ __launch_bounds__(256) void sample_tile_i8(
    const float* __restrict__ slots, const unsigned* __restrict__ cursor,
    const unsigned* __restrict__ ovf_cnt, const int* __restrict__ ovf,
    const float* __restrict__ x, const float* __restrict__ y,
    const uint2* __restrict__ t0, const uint2* __restrict__ t1,
    const uint2* __restrict__ t2, const uint2* __restrict__ t3,
    const uint2* __restrict__ t4, const float* __restrict__ deqs,
    float* __restrict__ out, int P) {
  __shared__ uint2 lds[LDS_CAP];
  int g = blockIdx.x;
  float d0 = deqs[0], d1 = deqs[1], d2 = deqs[2], d3 = deqs[3], d4 = deqs[4];
  Win wdum = {0, 0, 1, 1, 0};

  if (g >= NGRP) {
    int n = min((int)*ovf_cnt, OVF_CAP);
    int stride = (gridDim.x - NGRP) * 256;
    for (int i = (g - NGRP) * 256 + (int)threadIdx.x; i < n; i += stride) {
      int p = ovf[i];
      float xn = x[p] * 2.0f - 1.0f;
      float yn = y[p] * 2.0f - 1.0f;
      float* orow = out + (size_t)p * 40u;
      float res[8];
      sample_i8<64>(lds, wdum, false, t0, xn, yn, d0, res);   store8(orow + 0, res);
      sample_i8<128>(lds, wdum, false, t1, xn, yn, d1, res);  store8(orow + 8, res);
      sample_i8<256>(lds, wdum, false, t2, xn, yn, d2, res);  store8(orow + 16, res);
      sample_i8<512>(lds, wdum, false, t3, xn, yn, d3, res);  store8(orow + 24, res);
      sample_i8<1024>(lds, wdum, false, t4, xn, yn, d4, res); store8(orow + 32, res);
    }
    return;
  }

  int cnt = min((int)cursor[g], CAP);
  if (cnt == 0) return;

  int gx = g & 63, gy = g >> 6;
  float xlo = (float)gx * (1.0f / 64.0f);
  float xhi = (float)(gx + 1) * (1.0f / 64.0f);
  float ylo = (float)gy * (1.0f / 64.0f);
  float yhi = (float)(gy + 1) * (1.0f / 64.0f);

  Win w0 = mkwin<64>(xlo, xhi, ylo, yhi, 0);
  Win w1 = mkwin<128>(xlo, xhi, ylo, yhi, w0.base + 2 * w0.ww * w0.wh);
  Win w2 = mkwin<256>(xlo, xhi, ylo, yhi, w1.base + 2 * w1.ww * w1.wh);
  Win w3 = mkwin<512>(xlo, xhi, ylo, yhi, w2.base + 2 * w2.ww * w2.wh);
  Win w4 = mkwin<1024>(xlo, xhi, ylo, yhi, w3.base + 2 * w3.ww * w3.wh);
  int total = w4.base + 2 * w4.ww * w4.wh;
  bool use_lds = (total <= LDS_CAP);

  if (use_lds) {
    stage_i8<64>(lds, w0, t0);
    stage_i8<128>(lds, w1, t1);
    stage_i8<256>(lds, w2, t2);
    stage_i8<512>(lds, w3, t3);
    stage_i8<1024>(lds, w4, t4);
    __syncthreads();
  }

  const float* gs = slots + (size_t)g * CAP * 3u;
  for (int i = (int)threadIdx.x; i < cnt; i += 256) {
    const float* sp = gs + (size_t)i * 3u;
    float xn = sp[0], yn = sp[1];
    int q = __float_as_int(sp[2]);
    float* orow = out + (size_t)q * 40u;
    float res[8];
    sample_i8<64>(lds, w0, use_lds, t0, xn, yn, d0, res);   store8(orow + 0, res);
    sample_i8<128>(lds, w1, use_lds, t1, xn, yn, d1, res);  store8(orow + 8, res);
    sample_i8<256>(lds, w2, use_lds, t2, xn, yn, d2, res);  store8(orow + 16, res);
    sample_i8<512>(lds, w3, use_lds, t3, xn, yn, d3, res);  store8(orow + 24, res);
    sample_i8<1024>(lds, w4, use_lds, t4, xn, yn, d4, res); store8(orow + 32, res);
  }
}

// ==== tiny-ws fallback: direct fp32 ====
template <int W>
__device__ __forceinline__ void sample_level_direct(
    const float* __restrict__ t, float xv, float yv, float* __restrict__ o) {
  float acc[8];
#pragma unroll
  for (int i = 0; i < 8; ++i) acc[i] = 0.0f;
  float xn = xv * 2.0f - 1.0f;
  float yn = yv * 2.0f - 1.0f;
#pragma unroll
  for (int cell = 0; cell < 2; ++cell) {
    const float off = 0.5f * (float)cell;
    float ix = (xn + 1.0f) * 0.5f * (float)(W - 1) + off;
    float iy = (yn + 1.0f) * 0.5f * (float)(W - 1) + off;
    float x0f = floorf(ix), y0f = floorf(iy);
    float wx = ix - x0f, wy = iy - y0f;
    int x0 = (int)x0f; x0 = min(max(x0, 0), W - 1);
    int y0 = (int)y0f; y0 = min(max(y0, 0), W - 1);
    int x1 = min(x0 + 1, W - 1);
    int y1 = min(y0 + 1, W - 1);
    float w00 = (1.0f - wx) * (1.0f - wy);
    float w01 = wx * (1.0f - wy);
    float w10 = (1.0f - wx) * wy;
    float w11 = wx * wy;
    size_t i00 = (size_t)y0 * W + x0;
    size_t i01 = (size_t)y0 * W + x1;
    size_t i10 = (size_t)y1 * W + x0;
    size_t i11 = (size_t)y1 * W + x1;
#pragma unroll
    for (int c = 0; c < 8; ++c) {
      const float* pc = t + (size_t)cell * 8u * (size_t)W * (size_t)W +
                        (size_t)c * (size_t)W * (size_t)W;
      acc[c] += pc[i00] * w00 + pc[i01] * w01 + pc[i10] * w10 + pc[i11] * w11;
    }
  }
#pragma unroll
  for (int i = 0; i < 8; ++i) o[i] = acc[i];
}

__global__ __launch_bounds__(256) void sample_kernel_direct(
    const float* __restrict__ x, const float* __restrict__ y,
    const float* __restrict__ t0, const float* __restrict__ t1,
    const float* __restrict__ t2, const float* __restrict__ t3,
    const float* __restrict__ t4, float* __restrict__ out, int P) {
  int p = blockIdx.x * blockDim.x + threadIdx.x;
  if (p >= P) return;
  float xv = x[p];
  float yv = y[p];
  float o[8];
  float* orow = out + (size_t)p * 40u;
  sample_level_direct<64>(t0, xv, yv, o);
#pragma unroll
  for (int i = 0; i < 8; ++i) orow[0 + i] = o[i];
  sample_level_direct<128>(t1, xv, yv, o);
#pragma unroll
  for (int i = 0; i < 8; ++i) orow[8 + i] = o[i];
  sample_level_direct<256>(t2, xv, yv, o);
#pragma unroll
  for (int i = 0; i < 8; ++i) orow[16 + i] = o[i];
  sample_level_direct<512>(t3, xv, yv, o);
#pragma unroll
  for (int i = 0; i < 8; ++i) orow[24 + i] = o[i];
  sample_level_direct<1024>(t4, xv, yv, o);
#pragma unroll
  for (int i = 0; i < 8; ++i) orow[32 + i] = o[i];
}

extern "C" void kernel_launch(void* const* d_in, const int* in_sizes, int n_in,
                              void* d_out, int out_size, void* d_ws, size_t ws_size,
                              hipStream_t stream) {
  const float* x = (const float*)d_in[0];
  const float* y = (const float*)d_in[1];
  const float* tabs[5] = {(const float*)d_in[2], (const float*)d_in[3],
                          (const float*)d_in[4], (const float*)d_in[5],
                          (const float*)d_in[6]};
  float* out = (float*)d_out;
  const int P = in_sizes[0];

  const size_t offs[5] = {0, 8192, 40960, 172032, 696320};

  unsigned* cursor = (unsigned*)((char*)d_ws + WS_CURS);
  unsigned* ovf_cnt = (unsigned*)((char*)d_ws + WS_OVFC);
  int* ovf = (int*)((char*)d_ws + WS_OVF);
  float* slots = (float*)((char*)d_ws + WS_SLOT);

  if (ws_size >= WS_END_BF16 && P <= 1000448) {
    uint4* tb = (uint4*)((char*)d_ws + WS_TAB);
    (void)hipMemsetAsync((char*)d_ws, 0, WS_OVFC + 4, stream);
    scatter_bins_kernel<<<NSCAT, 512, 0, stream>>>(x, y, P, cursor, ovf_cnt,
                                                   ovf, slots);
    transform_kernel<<<10912, 256, 0, stream>>>(
        tabs[0], tabs[1], tabs[2], tabs[3], tabs[4], tb);
    sample_tile_bf16<<<NGRP, 256, 0, stream>>>(
        slots, cursor, tb + offs[0], tb + offs[1], tb + offs[2], tb + offs[3],
        tb + offs[4], out);
    sample_ovf_bf16<<<32, 256, 0, stream>>>(
        ovf_cnt, ovf, x, y, tb + offs[0], tb + offs[1], tb + offs[2],
        tb + offs[3], tb + offs[4], out);
  } else if (ws_size >= WS_END_I8 && P <= 1000448) {
    float* deq = (float*)((char*)d_ws + WS_DEQ);
    float* inv = (float*)((char*)d_ws + WS_INV);
    unsigned* partials = (unsigned*)((char*)d_ws + WS_PART);
    uint2* tb = (uint2*)((char*)d_ws + WS_TAB);
    (void)hipMemsetAsync((char*)d_ws, 0, WS_OVFC + 4, stream);
    absmax_scatter_kernel<<<NSCAT_I8 + 5456, 256, 0, stream>>>(
        tabs[0], tabs[1], tabs[2], tabs[3], tabs[4], partials, x, y, P, cursor,
        ovf_cnt, ovf, slots);
    finalize_scales_kernel<<<1, 256, 0, stream>>>(partials, deq, inv);
    quant_kernel<<<10912, 256, 0, stream>>>(
        tabs[0], tabs[1], tabs[2], tabs[3], tabs[4], tb, inv);
    sample_tile_i8<<<NGRP + 32, 256, 0, stream>>>(
        slots, cursor, ovf_cnt, ovf, x, y, tb + offs[0], tb + offs[1],
        tb + offs[2], tb + offs[3], tb + offs[4], deq, out, P);
  } else {
    sample_kernel_direct<<<(P + 255) / 256, 256, 0, stream>>>(
        x, y, tabs[0], tabs[1], tabs[2], tabs[3], tabs[4], out, P);
  }
}